// Round 3
// baseline (205.636 us; speedup 1.0000x reference)
//
#include <hip/hip_runtime.h>
#include <math.h>

// ---------------------------------------------------------------------------
// multi_head_attention: B=2, S=2048, D=1024, H=16, Hd=64, fp32 in/out.
// R12 = R11 resubmitted (round 2 bench died at container level; kernel audit
//       found no fault/hang path — see session journal).
// R11: attn LDS pressure halved -- V is no longer staged in LDS at all.
//      The V read-swizzle cancels the write-swizzle, so V fragments are
//      plain coalesced global loads (L1-served, all 4 waves share lines),
//      double-buffered in registers one chunk ahead. K stays LDS-staged
//      (4-deep, 32KB). Per-round LDS demand drops 1790->~900 cy (R10's
//      measured critical pipe: 128KB/round read for 32KB unique); MFMA
//      (1242 cy/SIMD/round) becomes the limit. vmcnt counted per-region
//      (10 ops/region) so in-region reordering can't break the waits.
//      R10's exp||qk||pv single-region pipeline retained. GEMMs = R6 exact.
// ---------------------------------------------------------------------------

using bf16   = __bf16;
using bf16x8 = __attribute__((ext_vector_type(8))) __bf16;
using bf16x4 = __attribute__((ext_vector_type(4))) __bf16;
using f32x4  = __attribute__((ext_vector_type(4))) float;

#define MFMA16(a, b, c) __builtin_amdgcn_mfma_f32_16x16x32_bf16((a), (b), (c), 0, 0, 0)
#define WAIT_VM0() asm volatile("s_waitcnt vmcnt(0)" ::: "memory")
#define WAITBAR(N) asm volatile("s_waitcnt vmcnt(" #N ")\n\ts_barrier" ::: "memory")

__device__ __forceinline__ bf16x8 ld8(const bf16* p) { return *(const bf16x8*)p; }

// async global->LDS, 16B/lane; lds_base is wave-uniform, HW adds lane*16.
__device__ __forceinline__ void ldg_lds16(bf16* lds_base, const bf16* g) {
    __builtin_amdgcn_global_load_lds(
        (const __attribute__((address_space(1))) void*)g,
        (__attribute__((address_space(3))) void*)lds_base, 16, 0, 0);
}

__device__ __forceinline__ float fast_exp2(float x) {
#if __has_builtin(__builtin_amdgcn_exp2f)
    return __builtin_amdgcn_exp2f(x);
#else
    return exp2f(x);
#endif
}

// ---------------------------------------------------------------------------
// Merged prep: z=0..3 transpose+convert W*; z=4 convert x -> bf16.
// ---------------------------------------------------------------------------
__global__ __launch_bounds__(256) void prep_kernel(
    const float* __restrict__ x, const float* __restrict__ Wq,
    const float* __restrict__ Wk, const float* __restrict__ Wv,
    const float* __restrict__ Wo, bf16* __restrict__ xb,
    bf16* __restrict__ WtBase) {
    const int z = blockIdx.z;
    const int tid = threadIdx.x;
    if (z == 4) {
        int id = blockIdx.y * 32 + blockIdx.x;      // 0..1023
#pragma unroll
        for (int k = 0; k < 4; ++k) {
            int i = id * 4096 + k * 1024 + tid * 4;
            float4 v = *(const float4*)&x[i];
            bf16x4 o = { (bf16)v.x, (bf16)v.y, (bf16)v.z, (bf16)v.w };
            *(bf16x4*)&xb[i] = o;
        }
        return;
    }
    __shared__ float tile[32][33];
    const float* W = (z == 0) ? Wq : (z == 1) ? Wk : (z == 2) ? Wv : Wo;
    bf16* Wt = WtBase + (size_t)z * 1024 * 1024;
    const int tx = tid & 31, ty = tid >> 5;          // 32 x 8
    const int x0 = blockIdx.x * 32, y0 = blockIdx.y * 32;
#pragma unroll
    for (int i = 0; i < 4; ++i)
        tile[ty + i * 8][tx] = W[(size_t)(y0 + ty + i * 8) * 1024 + x0 + tx];
    __syncthreads();
#pragma unroll
    for (int i = 0; i < 4; ++i)
        Wt[(size_t)(x0 + ty + i * 8) * 1024 + y0 + tx] = (bf16)tile[tx][ty + i * 8];
}

// ---------------------------------------------------------------------------
// 128x128 GEMM core, async double-buffered (R6 exact).
// ---------------------------------------------------------------------------
__device__ __forceinline__ void gemm_stage(const bf16* __restrict__ src, int r0,
                                           int k0, bf16* dst, int w, int lane) {
#pragma unroll
    for (int c = 0; c < 2; ++c) {
        int flat = (w * 2 + c) * 64 + lane;
        int row = flat >> 2, cc = flat & 3;
        int gk = (cc ^ ((row >> 1) & 3)) * 8;
        ldg_lds16(dst + (size_t)(w * 2 + c) * 512,
                  src + (size_t)(r0 + row) * 1024 + k0 + gk);
    }
}

__device__ __forceinline__ void gemm_core_128(const bf16* __restrict__ A,
                                              const bf16* __restrict__ Bt,
                                              int m0, int n0,
                                              bf16* As, bf16* Bs,   // each 2*4096
                                              f32x4 (&acc)[4][4]) {
    const int tid = threadIdx.x, lane = tid & 63, w = tid >> 6;
    const int lo = lane & 15, quad = lane >> 4;
    const int wm = w >> 1, wn = w & 1;

    gemm_stage(A,  m0, 0, As, w, lane);
    gemm_stage(Bt, n0, 0, Bs, w, lane);
    WAIT_VM0();
    __syncthreads();

    for (int it = 0; it < 32; ++it) {
        const int buf = it & 1;
        if (it + 1 < 32) {
            gemm_stage(A,  m0, (it + 1) * 32, As + (buf ^ 1) * 4096, w, lane);
            gemm_stage(Bt, n0, (it + 1) * 32, Bs + (buf ^ 1) * 4096, w, lane);
        }
        const bf16* Ab = As + buf * 4096;
        const bf16* Bb = Bs + buf * 4096;
        bf16x8 af[4], bq[4];
#pragma unroll
        for (int t = 0; t < 4; ++t) {
            int r = wm * 64 + t * 16 + lo;
            af[t] = ld8(&Ab[r * 32 + ((quad ^ ((r >> 1) & 3)) * 8)]);
        }
#pragma unroll
        for (int t = 0; t < 4; ++t) {
            int r = wn * 64 + t * 16 + lo;
            bq[t] = ld8(&Bb[r * 32 + ((quad ^ ((r >> 1) & 3)) * 8)]);
        }
#pragma unroll
        for (int mt = 0; mt < 4; ++mt)
#pragma unroll
            for (int nt = 0; nt < 4; ++nt)
                acc[mt][nt] = MFMA16(af[mt], bq[nt], acc[mt][nt]);
        WAIT_VM0();
        __syncthreads();
    }
}

// Fused QKV projection. z=0 -> Q (scaled log2e/8), z=1 -> K, z=2 -> V
// transposed [B][H][Hd][S_perm] via LDS-transpose epilogue; the s coordinate
// is permuted within each 32-key group: col' keeps attn's PV slot mapping
// slot = quad*8 + T*4 + o  <->  key = T*16 + quad*4 + o.
__global__ __launch_bounds__(256, 3) void qkv_gemm_kernel(
    const bf16* __restrict__ Xb, const bf16* __restrict__ Wts,
    const float* __restrict__ bq, const float* __restrict__ bk,
    const float* __restrict__ bv,
    bf16* __restrict__ Qo, bf16* __restrict__ Ko, bf16* __restrict__ Vto) {
    __shared__ bf16 Smem[4 * 4096];
    bf16* As = Smem;
    bf16* Bs = Smem + 2 * 4096;
    const int z = blockIdx.z;
    const bf16*  Bt   = Wts + (size_t)z * 1024 * 1024;
    const float* bias = (z == 0) ? bq : (z == 1) ? bk : bv;
    const int m0 = blockIdx.y * 128, n0 = blockIdx.x * 128;

    f32x4 acc[4][4] = {};
    gemm_core_128(Xb, Bt, m0, n0, As, Bs, acc);

    const int tid = threadIdx.x;
    const int lane = tid & 63, w = tid >> 6;
    const int lo = lane & 15, quad = lane >> 4;
    const int wm = w >> 1, wn = w & 1;
    const float QSCALE = 0.125f * 1.44269504088896f;  // 1/sqrt(64) * log2(e)

    if (z == 2) {
        // ---- V: transpose via LDS (two 128n x 64m half-tiles, stride 68) ----
        bf16* T = Smem;                      // 128*68 = 8704 elems
        const int b = m0 >> 11;
        const int s_base = m0 & 2047;
#pragma unroll
        for (int half = 0; half < 2; ++half) {
            __syncthreads();
            if (wm == half) {
#pragma unroll
                for (int nt = 0; nt < 4; ++nt)
#pragma unroll
                    for (int mt = 0; mt < 4; ++mt)
#pragma unroll
                        for (int r = 0; r < 4; ++r) {
                            int nn = wn * 64 + nt * 16 + lo;
                            int mm = mt * 16 + quad * 4 + r;
                            T[nn * 68 + mm] = (bf16)(acc[mt][nt][r] + bias[n0 + nn]);
                        }
            }
            __syncthreads();
#pragma unroll
            for (int p = 0; p < 8; ++p) {
                int pos = p * 1024 + tid * 4;
                int row = pos >> 6, col = pos & 63;
                int n = n0 + row, h = n >> 6, hd = n & 63;
                // permute key within its 32-group: slot = q4*8 + T16*4 + o
                int colp = (col & 32) | (((col >> 2) & 3) << 3)
                         | (((col >> 4) & 1) << 2) | (col & 3);
                bf16x4 v = *(const bf16x4*)&T[row * 68 + col];
                *(bf16x4*)&Vto[((size_t)((b * 16 + h) * 64 + hd) << 11)
                               + s_base + half * 64 + colp] = v;
            }
        }
    } else {
#pragma unroll
        for (int mt = 0; mt < 4; ++mt)
#pragma unroll
            for (int nt = 0; nt < 4; ++nt)
#pragma unroll
                for (int r = 0; r < 4; ++r) {
                    int m = m0 + wm * 64 + mt * 16 + quad * 4 + r;
                    int n = n0 + wn * 64 + nt * 16 + lo;
                    float v = acc[mt][nt][r] + bias[n];
                    int b = m >> 11, s = m & 2047, h = n >> 6, hd = n & 63;
                    if (z == 0)
                        Qo[((size_t)((b * 16 + h) * 2048 + s) << 6) + hd] = (bf16)(v * QSCALE);
                    else
                        Ko[((size_t)((b * 16 + h) * 2048 + s) << 6) + hd] = (bf16)v;
                }
    }
}

// ---------------------------------------------------------------------------
// Output projection, 64x128 tiles (512 blocks = 2/CU), double-buffered (R6).
// ---------------------------------------------------------------------------
__global__ __launch_bounds__(256, 2) void out_gemm_kernel(
    const bf16* __restrict__ A, const bf16* __restrict__ Bt,
    const float* __restrict__ bo, float* __restrict__ Co) {
    __shared__ bf16 As[2 * 2048];
    __shared__ bf16 Bs[2 * 4096];
    const int tid = threadIdx.x, lane = tid & 63, w = tid >> 6;
    const int lo = lane & 15, quad = lane >> 4;
    const int wm = w >> 1, wn = w & 1;
    const int m0 = blockIdx.y * 64, n0 = blockIdx.x * 128;

    auto stageA = [&](int k0, bf16* dst) {
        int flat = w * 64 + lane;
        int row = flat >> 2, cc = flat & 3;
        int gk = (cc ^ ((row >> 1) & 3)) * 8;
        ldg_lds16(dst + (size_t)w * 512, A + (size_t)(m0 + row) * 1024 + k0 + gk);
    };
    auto stageB = [&](int k0, bf16* dst) {
#pragma unroll
        for (int c = 0; c < 2; ++c) {
            int flat = (w * 2 + c) * 64 + lane;
            int row = flat >> 2, cc = flat & 3;
            int gk = (cc ^ ((row >> 1) & 3)) * 8;
            ldg_lds16(dst + (size_t)(w * 2 + c) * 512,
                      Bt + (size_t)(n0 + row) * 1024 + k0 + gk);
        }
    };

    f32x4 acc[2][4] = {};
    stageA(0, As);
    stageB(0, Bs);
    WAIT_VM0();
    __syncthreads();

    for (int it = 0; it < 32; ++it) {
        const int buf = it & 1;
        if (it + 1 < 32) {
            stageA((it + 1) * 32, As + (buf ^ 1) * 2048);
            stageB((it + 1) * 32, Bs + (buf ^ 1) * 4096);
        }
        const bf16* Ab = As + buf * 2048;
        const bf16* Bb = Bs + buf * 4096;
        bf16x8 af[2], bq[4];
#pragma unroll
        for (int t = 0; t < 2; ++t) {
            int r = wm * 32 + t * 16 + lo;
            af[t] = ld8(&Ab[r * 32 + ((quad ^ ((r >> 1) & 3)) * 8)]);
        }
#pragma unroll
        for (int t = 0; t < 4; ++t) {
            int r = wn * 64 + t * 16 + lo;
            bq[t] = ld8(&Bb[r * 32 + ((quad ^ ((r >> 1) & 3)) * 8)]);
        }
#pragma unroll
        for (int mt = 0; mt < 2; ++mt)
#pragma unroll
            for (int nt = 0; nt < 4; ++nt)
                acc[mt][nt] = MFMA16(af[mt], bq[nt], acc[mt][nt]);
        WAIT_VM0();
        __syncthreads();
    }

#pragma unroll
    for (int mt = 0; mt < 2; ++mt)
#pragma unroll
        for (int nt = 0; nt < 4; ++nt)
#pragma unroll
            for (int r = 0; r < 4; ++r) {
                int m = m0 + wm * 32 + mt * 16 + quad * 4 + r;
                int n = n0 + wn * 64 + nt * 16 + lo;
                Co[(size_t)m * 1024 + n] = acc[mt][nt][r] + bo[n];
            }
}

// ---------------------------------------------------------------------------
// Flash attention R11: S^T formulation, K via LDS, V via registers.
// Grid 512 x 256 (4 waves). Block = 128 q-rows of one (b,h); each wave owns
// 32 q (2 q-tiles as MFMA n-tiles). 64-key chunks.
//   K: 4-deep LDS staging (32KB), staged 2 chunks ahead, swizzled reads.
//   V: the LDS read-swizzle cancels the write-swizzle, so V frags are plain
//      global loads Vt[(nt*16+lo)*2048 + s0 + (kc*4+quad)*8] -- L1-served
//      (all 4 waves read the same lines, 8KB/chunk << 32KB L1). Prefetched
//      into registers one region ahead (VA/VB ping-pong, 8 dwordx4/chunk).
// Each region issues exactly 10 vm ops (8 V-loads + 2 K-stages), so the
// counted WAITBAR(10) retires the ENTIRE previous region regardless of
// compiler reordering inside a region: K(i+1) staged + V(i) in regs.
// Per-step single scheduling region: exp(S_i) || qk(i+1) || pv(V_i).
// ---------------------------------------------------------------------------
__global__ __launch_bounds__(256, 2) void attn_kernel(
    const bf16* __restrict__ Q, const bf16* __restrict__ K,
    const bf16* __restrict__ Vt, bf16* __restrict__ AO) {
    __shared__ bf16 Ks[4][64 * 64];
    const int tid = threadIdx.x, w = tid >> 6, lane = tid & 63;
    const int lo = lane & 15, quad = lane >> 4;
    const int blk = blockIdx.x;
    const int bh = (blk & 7) | ((blk >> 7) << 3);  // same-head -> same XCD
    const int qb = (blk >> 3) & 15;
    const int q0 = qb * 128 + w * 32;

    const bf16* Qb = Q + ((size_t)bh * 2048 + q0) * 64;
    const bf16* Kb = K + (size_t)bh * 2048 * 64;
    const bf16* Vb = Vt + (size_t)bh * 64 * 2048;
    // per-lane V base: hd row = lo (+nt*16 per frag), key slot = quad
    const bf16* Vl = Vb + (size_t)lo * 2048 + quad * 8;

    // Q B-fragments: n-row = qt*16+lo, k = ks*32+quad*8
    bf16x8 qa[2][2];
#pragma unroll
    for (int qt = 0; qt < 2; ++qt)
#pragma unroll
        for (int ks = 0; ks < 2; ++ks)
            qa[qt][ks] = ld8(&Qb[(qt * 16 + lo) * 64 + ks * 32 + quad * 8]);

    f32x4 O[2][4] = {};
    float l_acc[2] = { 0.f, 0.f };

    // stage one 64-key K chunk (2 ldg_lds/wave); swizzle s(row)=row&7.
    auto stageK = [&](int s0, int buf) {
#pragma unroll
        for (int c = 0; c < 2; ++c) {
            int flat = (w * 2 + c) * 64 + lane;
            int row = flat >> 3, cc = flat & 7;
            int g = (cc ^ (row & 7)) * 8;
            ldg_lds16(&Ks[buf][(w * 2 + c) * 512], &Kb[(size_t)(s0 + row) * 64 + g]);
        }
    };

    // load V frags for chunk at s0 into registers (8 global_load_dwordx4)
    auto vload = [&](int s0, bf16x8 (&Vr)[2][4]) {
#pragma unroll
        for (int kc = 0; kc < 2; ++kc)
#pragma unroll
            for (int nt = 0; nt < 4; ++nt)
                Vr[kc][nt] = ld8(Vl + (size_t)nt * 16 * 2048 + s0 + kc * 32);
    };

    const int swz = lo & 7;  // read-side swizzle for K rows t*16+lo

    // ---- S^T = K * Q^T from Ks[nb] : 4 key m-tiles x 2 q n-tiles x 2 k ----
    auto qk = [&](int nb, f32x4 (&S)[2][4]) {
        const bf16* Kt = &Ks[nb][0];
#pragma unroll
        for (int qt = 0; qt < 2; ++qt)
#pragma unroll
            for (int t = 0; t < 4; ++t)
                S[qt][t] = f32x4{ 0.f, 0.f, 0.f, 0.f };
#pragma unroll
        for (int t = 0; t < 4; ++t) {
            int r = t * 16 + lo;
#pragma unroll
            for (int ks = 0; ks < 2; ++ks) {
                bf16x8 kf = ld8(&Kt[r * 64 + (((quad + 4 * ks) ^ swz) * 8)]);
                S[0][t] = MFMA16(kf, qa[0][ks], S[0][t]);
                S[1][t] = MFMA16(kf, qa[1][ks], S[1][t]);
            }
        }
    };

    // ---- exp(Sin) -> pa (PV A-frags, keys slot-permuted) + l_acc ----
    auto expP = [&](f32x4 (&Sin)[2][4], bf16x8 (&pa)[2][2]) {
#pragma unroll
        for (int qt = 0; qt < 2; ++qt)
#pragma unroll
            for (int kc = 0; kc < 2; ++kc) {
                float e0 = fast_exp2(Sin[qt][2 * kc][0]);
                float e1 = fast_exp2(Sin[qt][2 * kc][1]);
                float e2 = fast_exp2(Sin[qt][2 * kc][2]);
                float e3 = fast_exp2(Sin[qt][2 * kc][3]);
                float e4 = fast_exp2(Sin[qt][2 * kc + 1][0]);
                float e5 = fast_exp2(Sin[qt][2 * kc + 1][1]);
                float e6 = fast_exp2(Sin[qt][2 * kc + 1][2]);
                float e7 = fast_exp2(Sin[qt][2 * kc + 1][3]);
                l_acc[qt] += ((e0 + e1) + (e2 + e3)) + ((e4 + e5) + (e6 + e7));
                pa[qt][kc] = bf16x8{ (bf16)e0, (bf16)e1, (bf16)e2, (bf16)e3,
                                     (bf16)e4, (bf16)e5, (bf16)e6, (bf16)e7 };
            }
    };

    // ---- PV from register V frags ----
    auto pv = [&](bf16x8 (&Vr)[2][4], bf16x8 (&pa)[2][2]) {
#pragma unroll
        for (int kc = 0; kc < 2; ++kc)
#pragma unroll
            for (int nt = 0; nt < 4; ++nt) {
                O[0][nt] = MFMA16(pa[0][kc], Vr[kc][nt], O[0][nt]);
                O[1][nt] = MFMA16(pa[1][kc], Vr[kc][nt], O[1][nt]);
            }
    };

    // step i: exp(S_i) || S_{i+1}=qk || O+=P_i*V_i  (one region, no barrier)
    auto step = [&](f32x4 (&Sin)[2][4], f32x4 (&Sout)[2][4], int nb,
                    bf16x8 (&Vr)[2][4]) {
        bf16x8 pa[2][2];
        expP(Sin, pa);
        qk(nb, Sout);
        pv(Vr, pa);
    };

    bf16x8 VA[2][4], VB[2][4];
    vload(0, VB);                   // V(0)
    stageK(0, 0);
    stageK(64, 1);
    WAITBAR(0);                     // drain once: K0,K1 staged, V0 in regs

    f32x4 Sa[2][4], Sb[2][4];
    qk(0, Sa);

    for (int it = 0; it < 30; it += 2) {
        // step it (even): consume VB=V(it), load VA=V(it+1)
        vload((it + 1) * 64, VA);
        stageK((it + 2) * 64, (it + 2) & 3);
        WAITBAR(10);                // retires prev region: K(it+1) + V(it)
        step(Sa, Sb, (it + 1) & 3, VB);
        // step it+1 (odd): consume VA, load VB=V(it+2)
        vload((it + 2) * 64, VB);
        stageK((it + 3) * 64, (it + 3) & 3);
        WAITBAR(10);                // retires prev region: K(it+2) + V(it+1)
        step(Sb, Sa, (it + 2) & 3, VA);
    }
    // step 30: consume VB=V(30), load VA=V(31); K(31) staged last iter
    vload(31 * 64, VA);
    WAITBAR(8);                     // retires {V(30)x8, K(31)x2}
    step(Sa, Sb, 3, VB);            // exp(S30) || qk(31) || PV(30)
    // step 31: no loads left
    WAIT_VM0();                     // V(31) in regs
    {
        bf16x8 pa[2][2];
        expP(Sb, pa);
        pv(VA, pa);
    }

    // ---- epilogue: l lives at q=lo; redistribute to C-rows via shfl ----
    const int bb = bh >> 4, h = bh & 15;
#pragma unroll
    for (int qt = 0; qt < 2; ++qt) {
        float lt = l_acc[qt];
        lt += __shfl_xor(lt, 16, 64);
        lt += __shfl_xor(lt, 32, 64);   // total l for q = qt*16 + lo
        const size_t outbase = ((size_t)(bb * 2048 + q0 + qt * 16)) * 1024 + h * 64;
#pragma unroll
        for (int r = 0; r < 4; ++r) {
            float rl = 1.0f / __shfl(lt, quad * 4 + r, 64);
            size_t rowoff = outbase + (size_t)(quad * 4 + r) * 1024;
#pragma unroll
            for (int nt = 0; nt < 4; ++nt)
                AO[rowoff + nt * 16 + lo] = (bf16)(O[qt][nt][r] * rl);
        }
    }
}

// ---------------------------------------------------------------------------
extern "C" void kernel_launch(void* const* d_in, const int* in_sizes, int n_in,
                              void* d_out, int out_size, void* d_ws, size_t ws_size,
                              hipStream_t stream) {
    const float* x  = (const float*)d_in[0];
    const float* Wq = (const float*)d_in[1];
    const float* bq = (const float*)d_in[2];
    const float* Wk = (const float*)d_in[3];
    const float* bk = (const float*)d_in[4];
    const float* Wv = (const float*)d_in[5];
    const float* bv = (const float*)d_in[6];
    const float* Wo = (const float*)d_in[7];
    const float* bo = (const float*)d_in[8];
    float* out = (float*)d_out;

    bf16* wsb = (bf16*)d_ws;
    const size_t M1 = 1024u * 1024u;
    bf16* Xb  = wsb;
    bf16* AO  = wsb;            // aliases Xb (Xb dead after qkv_gemm)
    bf16* Wt  = wsb + 4 * M1;
    bf16* Qw  = wsb + 8 * M1;
    bf16* Kw  = wsb + 12 * M1;
    bf16* Vtw = wsb + 16 * M1;

    prep_kernel<<<dim3(32, 32, 5), 256, 0, stream>>>(x, Wq, Wk, Wv, Wo, Xb, Wt);
    qkv_gemm_kernel<<<dim3(8, 32, 3), 256, 0, stream>>>(Xb, Wt, bq, bk, bv, Qw, Kw, Vtw);
    attn_kernel<<<512, 256, 0, stream>>>(Qw, Kw, Vtw, AO);
    out_gemm_kernel<<<dim3(8, 64), 256, 0, stream>>>(AO, Wt + 3 * M1, bo, out);
}

// Round 4
// 187.998 us; speedup vs baseline: 1.0938x; 1.0938x over previous
//
#include <hip/hip_runtime.h>
#include <math.h>

// ---------------------------------------------------------------------------
// multi_head_attention: B=2, S=2048, D=1024, H=16, Hd=64, fp32 in/out.
// R13: attn = R10 structure (V back in LDS -- R11's global-V regressed 43->72us:
//      scattered 16-line-per-instr V loads thrashed the TA/L1 path) but with
//      64 q per WAVE (2-wave blocks, 128 thr), halving per-CU LDS read traffic
//      (the R10 critical pipe): each wave reads the same 16KB K+V chunk but
//      does 2x MFMA with it. Grid 512 unchanged (2 blk/CU, 1 wave/SIMD,
//      ~280 VGPR OK under launch_bounds(128,1)). exp||qk||pv fused region +
//      4-deep staging + counted WAITBAR(8) as verified in R10. GEMMs = R6.
// ---------------------------------------------------------------------------

using bf16   = __bf16;
using bf16x8 = __attribute__((ext_vector_type(8))) __bf16;
using bf16x4 = __attribute__((ext_vector_type(4))) __bf16;
using f32x4  = __attribute__((ext_vector_type(4))) float;

#define MFMA16(a, b, c) __builtin_amdgcn_mfma_f32_16x16x32_bf16((a), (b), (c), 0, 0, 0)
#define WAIT_VM0() asm volatile("s_waitcnt vmcnt(0)" ::: "memory")
#define WAITBAR(N) asm volatile("s_waitcnt vmcnt(" #N ")\n\ts_barrier" ::: "memory")

__device__ __forceinline__ bf16x8 ld8(const bf16* p) { return *(const bf16x8*)p; }

// async global->LDS, 16B/lane; lds_base is wave-uniform, HW adds lane*16.
__device__ __forceinline__ void ldg_lds16(bf16* lds_base, const bf16* g) {
    __builtin_amdgcn_global_load_lds(
        (const __attribute__((address_space(1))) void*)g,
        (__attribute__((address_space(3))) void*)lds_base, 16, 0, 0);
}

__device__ __forceinline__ float fast_exp2(float x) {
#if __has_builtin(__builtin_amdgcn_exp2f)
    return __builtin_amdgcn_exp2f(x);
#else
    return exp2f(x);
#endif
}

// ---------------------------------------------------------------------------
// Merged prep: z=0..3 transpose+convert W*; z=4 convert x -> bf16.
// ---------------------------------------------------------------------------
__global__ __launch_bounds__(256) void prep_kernel(
    const float* __restrict__ x, const float* __restrict__ Wq,
    const float* __restrict__ Wk, const float* __restrict__ Wv,
    const float* __restrict__ Wo, bf16* __restrict__ xb,
    bf16* __restrict__ WtBase) {
    const int z = blockIdx.z;
    const int tid = threadIdx.x;
    if (z == 4) {
        int id = blockIdx.y * 32 + blockIdx.x;      // 0..1023
#pragma unroll
        for (int k = 0; k < 4; ++k) {
            int i = id * 4096 + k * 1024 + tid * 4;
            float4 v = *(const float4*)&x[i];
            bf16x4 o = { (bf16)v.x, (bf16)v.y, (bf16)v.z, (bf16)v.w };
            *(bf16x4*)&xb[i] = o;
        }
        return;
    }
    __shared__ float tile[32][33];
    const float* W = (z == 0) ? Wq : (z == 1) ? Wk : (z == 2) ? Wv : Wo;
    bf16* Wt = WtBase + (size_t)z * 1024 * 1024;
    const int tx = tid & 31, ty = tid >> 5;          // 32 x 8
    const int x0 = blockIdx.x * 32, y0 = blockIdx.y * 32;
#pragma unroll
    for (int i = 0; i < 4; ++i)
        tile[ty + i * 8][tx] = W[(size_t)(y0 + ty + i * 8) * 1024 + x0 + tx];
    __syncthreads();
#pragma unroll
    for (int i = 0; i < 4; ++i)
        Wt[(size_t)(x0 + ty + i * 8) * 1024 + y0 + tx] = (bf16)tile[tx][ty + i * 8];
}

// ---------------------------------------------------------------------------
// 128x128 GEMM core, async double-buffered (R6 exact).
// ---------------------------------------------------------------------------
__device__ __forceinline__ void gemm_stage(const bf16* __restrict__ src, int r0,
                                           int k0, bf16* dst, int w, int lane) {
#pragma unroll
    for (int c = 0; c < 2; ++c) {
        int flat = (w * 2 + c) * 64 + lane;
        int row = flat >> 2, cc = flat & 3;
        int gk = (cc ^ ((row >> 1) & 3)) * 8;
        ldg_lds16(dst + (size_t)(w * 2 + c) * 512,
                  src + (size_t)(r0 + row) * 1024 + k0 + gk);
    }
}

__device__ __forceinline__ void gemm_core_128(const bf16* __restrict__ A,
                                              const bf16* __restrict__ Bt,
                                              int m0, int n0,
                                              bf16* As, bf16* Bs,   // each 2*4096
                                              f32x4 (&acc)[4][4]) {
    const int tid = threadIdx.x, lane = tid & 63, w = tid >> 6;
    const int lo = lane & 15, quad = lane >> 4;
    const int wm = w >> 1, wn = w & 1;

    gemm_stage(A,  m0, 0, As, w, lane);
    gemm_stage(Bt, n0, 0, Bs, w, lane);
    WAIT_VM0();
    __syncthreads();

    for (int it = 0; it < 32; ++it) {
        const int buf = it & 1;
        if (it + 1 < 32) {
            gemm_stage(A,  m0, (it + 1) * 32, As + (buf ^ 1) * 4096, w, lane);
            gemm_stage(Bt, n0, (it + 1) * 32, Bs + (buf ^ 1) * 4096, w, lane);
        }
        const bf16* Ab = As + buf * 4096;
        const bf16* Bb = Bs + buf * 4096;
        bf16x8 af[4], bq[4];
#pragma unroll
        for (int t = 0; t < 4; ++t) {
            int r = wm * 64 + t * 16 + lo;
            af[t] = ld8(&Ab[r * 32 + ((quad ^ ((r >> 1) & 3)) * 8)]);
        }
#pragma unroll
        for (int t = 0; t < 4; ++t) {
            int r = wn * 64 + t * 16 + lo;
            bq[t] = ld8(&Bb[r * 32 + ((quad ^ ((r >> 1) & 3)) * 8)]);
        }
#pragma unroll
        for (int mt = 0; mt < 4; ++mt)
#pragma unroll
            for (int nt = 0; nt < 4; ++nt)
                acc[mt][nt] = MFMA16(af[mt], bq[nt], acc[mt][nt]);
        WAIT_VM0();
        __syncthreads();
    }
}

// Fused QKV projection. z=0 -> Q (scaled log2e/8), z=1 -> K, z=2 -> V
// transposed [B][H][Hd][S_perm] via LDS-transpose epilogue; the s coordinate
// is permuted within each 32-key group: col' keeps attn's PV slot mapping
// slot = quad*8 + T*4 + o  <->  key = T*16 + quad*4 + o.
__global__ __launch_bounds__(256, 3) void qkv_gemm_kernel(
    const bf16* __restrict__ Xb, const bf16* __restrict__ Wts,
    const float* __restrict__ bq, const float* __restrict__ bk,
    const float* __restrict__ bv,
    bf16* __restrict__ Qo, bf16* __restrict__ Ko, bf16* __restrict__ Vto) {
    __shared__ bf16 Smem[4 * 4096];
    bf16* As = Smem;
    bf16* Bs = Smem + 2 * 4096;
    const int z = blockIdx.z;
    const bf16*  Bt   = Wts + (size_t)z * 1024 * 1024;
    const float* bias = (z == 0) ? bq : (z == 1) ? bk : bv;
    const int m0 = blockIdx.y * 128, n0 = blockIdx.x * 128;

    f32x4 acc[4][4] = {};
    gemm_core_128(Xb, Bt, m0, n0, As, Bs, acc);

    const int tid = threadIdx.x;
    const int lane = tid & 63, w = tid >> 6;
    const int lo = lane & 15, quad = lane >> 4;
    const int wm = w >> 1, wn = w & 1;
    const float QSCALE = 0.125f * 1.44269504088896f;  // 1/sqrt(64) * log2(e)

    if (z == 2) {
        // ---- V: transpose via LDS (two 128n x 64m half-tiles, stride 68) ----
        bf16* T = Smem;                      // 128*68 = 8704 elems
        const int b = m0 >> 11;
        const int s_base = m0 & 2047;
#pragma unroll
        for (int half = 0; half < 2; ++half) {
            __syncthreads();
            if (wm == half) {
#pragma unroll
                for (int nt = 0; nt < 4; ++nt)
#pragma unroll
                    for (int mt = 0; mt < 4; ++mt)
#pragma unroll
                        for (int r = 0; r < 4; ++r) {
                            int nn = wn * 64 + nt * 16 + lo;
                            int mm = mt * 16 + quad * 4 + r;
                            T[nn * 68 + mm] = (bf16)(acc[mt][nt][r] + bias[n0 + nn]);
                        }
            }
            __syncthreads();
#pragma unroll
            for (int p = 0; p < 8; ++p) {
                int pos = p * 1024 + tid * 4;
                int row = pos >> 6, col = pos & 63;
                int n = n0 + row, h = n >> 6, hd = n & 63;
                // permute key within its 32-group: slot = q4*8 + T16*4 + o
                int colp = (col & 32) | (((col >> 2) & 3) << 3)
                         | (((col >> 4) & 1) << 2) | (col & 3);
                bf16x4 v = *(const bf16x4*)&T[row * 68 + col];
                *(bf16x4*)&Vto[((size_t)((b * 16 + h) * 64 + hd) << 11)
                               + s_base + half * 64 + colp] = v;
            }
        }
    } else {
#pragma unroll
        for (int mt = 0; mt < 4; ++mt)
#pragma unroll
            for (int nt = 0; nt < 4; ++nt)
#pragma unroll
                for (int r = 0; r < 4; ++r) {
                    int m = m0 + wm * 64 + mt * 16 + quad * 4 + r;
                    int n = n0 + wn * 64 + nt * 16 + lo;
                    float v = acc[mt][nt][r] + bias[n];
                    int b = m >> 11, s = m & 2047, h = n >> 6, hd = n & 63;
                    if (z == 0)
                        Qo[((size_t)((b * 16 + h) * 2048 + s) << 6) + hd] = (bf16)(v * QSCALE);
                    else
                        Ko[((size_t)((b * 16 + h) * 2048 + s) << 6) + hd] = (bf16)v;
                }
    }
}

// ---------------------------------------------------------------------------
// Output projection, 64x128 tiles (512 blocks = 2/CU), double-buffered (R6).
// ---------------------------------------------------------------------------
__global__ __launch_bounds__(256, 2) void out_gemm_kernel(
    const bf16* __restrict__ A, const bf16* __restrict__ Bt,
    const float* __restrict__ bo, float* __restrict__ Co) {
    __shared__ bf16 As[2 * 2048];
    __shared__ bf16 Bs[2 * 4096];
    const int tid = threadIdx.x, lane = tid & 63, w = tid >> 6;
    const int lo = lane & 15, quad = lane >> 4;
    const int wm = w >> 1, wn = w & 1;
    const int m0 = blockIdx.y * 64, n0 = blockIdx.x * 128;

    auto stageA = [&](int k0, bf16* dst) {
        int flat = w * 64 + lane;
        int row = flat >> 2, cc = flat & 3;
        int gk = (cc ^ ((row >> 1) & 3)) * 8;
        ldg_lds16(dst + (size_t)w * 512, A + (size_t)(m0 + row) * 1024 + k0 + gk);
    };
    auto stageB = [&](int k0, bf16* dst) {
#pragma unroll
        for (int c = 0; c < 2; ++c) {
            int flat = (w * 2 + c) * 64 + lane;
            int row = flat >> 2, cc = flat & 3;
            int gk = (cc ^ ((row >> 1) & 3)) * 8;
            ldg_lds16(dst + (size_t)(w * 2 + c) * 512,
                      Bt + (size_t)(n0 + row) * 1024 + k0 + gk);
        }
    };

    f32x4 acc[2][4] = {};
    stageA(0, As);
    stageB(0, Bs);
    WAIT_VM0();
    __syncthreads();

    for (int it = 0; it < 32; ++it) {
        const int buf = it & 1;
        if (it + 1 < 32) {
            stageA((it + 1) * 32, As + (buf ^ 1) * 2048);
            stageB((it + 1) * 32, Bs + (buf ^ 1) * 4096);
        }
        const bf16* Ab = As + buf * 2048;
        const bf16* Bb = Bs + buf * 4096;
        bf16x8 af[2], bq[4];
#pragma unroll
        for (int t = 0; t < 2; ++t) {
            int r = wm * 32 + t * 16 + lo;
            af[t] = ld8(&Ab[r * 32 + ((quad ^ ((r >> 1) & 3)) * 8)]);
        }
#pragma unroll
        for (int t = 0; t < 4; ++t) {
            int r = wn * 64 + t * 16 + lo;
            bq[t] = ld8(&Bb[r * 32 + ((quad ^ ((r >> 1) & 3)) * 8)]);
        }
#pragma unroll
        for (int mt = 0; mt < 2; ++mt)
#pragma unroll
            for (int nt = 0; nt < 4; ++nt)
                acc[mt][nt] = MFMA16(af[mt], bq[nt], acc[mt][nt]);
        WAIT_VM0();
        __syncthreads();
    }

#pragma unroll
    for (int mt = 0; mt < 2; ++mt)
#pragma unroll
        for (int nt = 0; nt < 4; ++nt)
#pragma unroll
            for (int r = 0; r < 4; ++r) {
                int m = m0 + wm * 32 + mt * 16 + quad * 4 + r;
                int n = n0 + wn * 64 + nt * 16 + lo;
                Co[(size_t)m * 1024 + n] = acc[mt][nt][r] + bo[n];
            }
}

// ---------------------------------------------------------------------------
// Flash attention R13: S^T formulation, 64 q per wave.
// Grid 512 x 128 (2 waves). Block = 128 q-rows of one (b,h); each wave owns
// 64 q (4 q-tiles as MFMA n-tiles). 64-key chunks, K+V 4-deep LDS (64KB),
// staged 2 chunks ahead, 8 ldg_lds/wave/chunk, counted WAITBAR(8).
//   S^T = K*Q^T : C col=lo -> q, row=quad*4+r -> key.
//   exps packed from C-regs into PV A-frags (slot quad*8+T*4+r <-> key
//   T*16+quad*4+r); V stored globally in this permuted key order.
// Per-step single scheduling region: exp(S_i) || qk(i+1) || pv(V_i)
// (Sa/Sb ping-pong, loop unrolled x2 -- no runtime-indexed reg arrays).
// 1 wave/SIMD: ~280 VGPR fits under launch_bounds(128,1) (no spill < ~450).
// ---------------------------------------------------------------------------
__global__ __launch_bounds__(128, 1) void attn_kernel(
    const bf16* __restrict__ Q, const bf16* __restrict__ K,
    const bf16* __restrict__ Vt, bf16* __restrict__ AO) {
    __shared__ bf16 Ks[4][64 * 64];
    __shared__ bf16 Vs[4][64 * 64];
    const int tid = threadIdx.x, w = tid >> 6, lane = tid & 63;
    const int lo = lane & 15, quad = lane >> 4;
    const int blk = blockIdx.x;
    const int bh = (blk & 7) | ((blk >> 7) << 3);  // same-head -> same XCD
    const int qb = (blk >> 3) & 15;
    const int q0 = qb * 128 + w * 64;              // wave owns 64 q-rows

    const bf16* Qb = Q + ((size_t)bh * 2048 + q0) * 64;
    const bf16* Kb = K + (size_t)bh * 2048 * 64;
    const bf16* Vb = Vt + (size_t)bh * 64 * 2048;

    // Q B-fragments: n-row = qt*16+lo, k = ks*32+quad*8
    bf16x8 qa[4][2];
#pragma unroll
    for (int qt = 0; qt < 4; ++qt)
#pragma unroll
        for (int ks = 0; ks < 2; ++ks)
            qa[qt][ks] = ld8(&Qb[(qt * 16 + lo) * 64 + ks * 32 + quad * 8]);

    f32x4 O[4][4] = {};
    float l_acc[4] = { 0.f, 0.f, 0.f, 0.f };

    // stage one 64-key K+V chunk (8 ldg_lds/wave); swizzle s(row)=row&7 both.
    auto stage = [&](int s0, int buf) {
#pragma unroll
        for (int c = 0; c < 4; ++c) {
            int sc = w * 4 + c;                    // section 0..7
            int flat = sc * 64 + lane;
            int row = flat >> 3, cc = flat & 7;
            int g = (cc ^ (row & 7)) * 8;
            ldg_lds16(&Ks[buf][sc * 512], &Kb[(size_t)(s0 + row) * 64 + g]);
            ldg_lds16(&Vs[buf][sc * 512], &Vb[(size_t)row * 2048 + s0 + g]);
        }
    };

    const int swz = lo & 7;  // read-side swizzle for rows t*16+lo

    // ---- S^T = K * Q^T from Ks[nb] : 4 key m-tiles x 4 q n-tiles x 2 k ----
    auto qk = [&](int nb, f32x4 (&S)[4][4]) {
        const bf16* Kt = &Ks[nb][0];
#pragma unroll
        for (int qt = 0; qt < 4; ++qt)
#pragma unroll
            for (int t = 0; t < 4; ++t)
                S[qt][t] = f32x4{ 0.f, 0.f, 0.f, 0.f };
#pragma unroll
        for (int t = 0; t < 4; ++t) {
            int r = t * 16 + lo;
#pragma unroll
            for (int ks = 0; ks < 2; ++ks) {
                bf16x8 kf = ld8(&Kt[r * 64 + (((quad + 4 * ks) ^ swz) * 8)]);
#pragma unroll
                for (int qt = 0; qt < 4; ++qt)
                    S[qt][t] = MFMA16(kf, qa[qt][ks], S[qt][t]);
            }
        }
    };

    // ---- exp(Sin) -> pa (PV A-frags, keys slot-permuted) + l_acc ----
    auto expP = [&](f32x4 (&Sin)[4][4], bf16x8 (&pa)[4][2]) {
#pragma unroll
        for (int qt = 0; qt < 4; ++qt)
#pragma unroll
            for (int kc = 0; kc < 2; ++kc) {
                float e0 = fast_exp2(Sin[qt][2 * kc][0]);
                float e1 = fast_exp2(Sin[qt][2 * kc][1]);
                float e2 = fast_exp2(Sin[qt][2 * kc][2]);
                float e3 = fast_exp2(Sin[qt][2 * kc][3]);
                float e4 = fast_exp2(Sin[qt][2 * kc + 1][0]);
                float e5 = fast_exp2(Sin[qt][2 * kc + 1][1]);
                float e6 = fast_exp2(Sin[qt][2 * kc + 1][2]);
                float e7 = fast_exp2(Sin[qt][2 * kc + 1][3]);
                l_acc[qt] += ((e0 + e1) + (e2 + e3)) + ((e4 + e5) + (e6 + e7));
                pa[qt][kc] = bf16x8{ (bf16)e0, (bf16)e1, (bf16)e2, (bf16)e3,
                                     (bf16)e4, (bf16)e5, (bf16)e6, (bf16)e7 };
            }
    };

    // ---- PV from Vs[cb]: V frags shared across all 4 q-tiles ----
    auto pv = [&](int cb, bf16x8 (&pa)[4][2]) {
        const bf16* Vl = &Vs[cb][0];
#pragma unroll
        for (int kc = 0; kc < 2; ++kc)
#pragma unroll
            for (int nt = 0; nt < 4; ++nt) {
                int r = nt * 16 + lo;
                bf16x8 vf = ld8(&Vl[r * 64 + ((((kc * 4 + quad) ^ swz)) * 8)]);
#pragma unroll
                for (int qt = 0; qt < 4; ++qt)
                    O[qt][nt] = MFMA16(pa[qt][kc], vf, O[qt][nt]);
            }
    };

    // step i: exp(S_i) || S_{i+1}=qk || O+=P_i*V_i  (one region, no barrier)
    auto step = [&](f32x4 (&Sin)[4][4], f32x4 (&Sout)[4][4], int cb, int nb) {
        bf16x8 pa[4][2];
        expP(Sin, pa);
        qk(nb, Sout);
        pv(cb, pa);
    };

    stage(0, 0);
    stage(64, 1);
    WAITBAR(8);                     // chunk0 ready; chunk1 (8 ops) in flight

    f32x4 Sa[4][4], Sb[4][4];
    qk(0, Sa);

    for (int it = 0; it < 30; it += 2) {
        stage((it + 2) * 64, (it + 2) & 3);
        WAITBAR(8);                 // chunk it+1 ready
        step(Sa, Sb, it & 3, (it + 1) & 3);
        stage((it + 3) * 64, (it + 3) & 3);
        WAITBAR(8);                 // chunk it+2 ready
        step(Sb, Sa, (it + 1) & 3, (it + 2) & 3);
    }
    WAITBAR(0);                     // chunk 31 ready
    step(Sa, Sb, 2, 3);             // exp(S30) || qk(31) || PV(30)
    {                               // tail: exp(S31) + PV(31)
        bf16x8 pa[4][2];
        expP(Sb, pa);
        pv(3, pa);
    }

    // ---- epilogue: l lives at q=lo; redistribute to C-rows via shfl ----
    const int bb = bh >> 4, h = bh & 15;
#pragma unroll
    for (int qt = 0; qt < 4; ++qt) {
        float lt = l_acc[qt];
        lt += __shfl_xor(lt, 16, 64);
        lt += __shfl_xor(lt, 32, 64);   // total l for q = qt*16 + lo
        const size_t outbase = ((size_t)(bb * 2048 + q0 + qt * 16)) * 1024 + h * 64;
#pragma unroll
        for (int r = 0; r < 4; ++r) {
            float rl = 1.0f / __shfl(lt, quad * 4 + r, 64);
            size_t rowoff = outbase + (size_t)(quad * 4 + r) * 1024;
#pragma unroll
            for (int nt = 0; nt < 4; ++nt)
                AO[rowoff + nt * 16 + lo] = (bf16)(O[qt][nt][r] * rl);
        }
    }
}

// ---------------------------------------------------------------------------
extern "C" void kernel_launch(void* const* d_in, const int* in_sizes, int n_in,
                              void* d_out, int out_size, void* d_ws, size_t ws_size,
                              hipStream_t stream) {
    const float* x  = (const float*)d_in[0];
    const float* Wq = (const float*)d_in[1];
    const float* bq = (const float*)d_in[2];
    const float* Wk = (const float*)d_in[3];
    const float* bk = (const float*)d_in[4];
    const float* Wv = (const float*)d_in[5];
    const float* bv = (const float*)d_in[6];
    const float* Wo = (const float*)d_in[7];
    const float* bo = (const float*)d_in[8];
    float* out = (float*)d_out;

    bf16* wsb = (bf16*)d_ws;
    const size_t M1 = 1024u * 1024u;
    bf16* Xb  = wsb;
    bf16* AO  = wsb;            // aliases Xb (Xb dead after qkv_gemm)
    bf16* Wt  = wsb + 4 * M1;
    bf16* Qw  = wsb + 8 * M1;
    bf16* Kw  = wsb + 12 * M1;
    bf16* Vtw = wsb + 16 * M1;

    prep_kernel<<<dim3(32, 32, 5), 256, 0, stream>>>(x, Wq, Wk, Wv, Wo, Xb, Wt);
    qkv_gemm_kernel<<<dim3(8, 32, 3), 256, 0, stream>>>(Xb, Wt, bq, bk, bv, Qw, Kw, Vtw);
    attn_kernel<<<512, 128, 0, stream>>>(Qw, Kw, Vtw, AO);
    out_gemm_kernel<<<dim3(8, 64), 256, 0, stream>>>(AO, Wt + 3 * M1, bo, out);
}

// Round 5
// 182.359 us; speedup vs baseline: 1.1276x; 1.0309x over previous
//
#include <hip/hip_runtime.h>
#include <math.h>

// ---------------------------------------------------------------------------
// multi_head_attention: B=2, S=2048, D=1024, H=16, Hd=64, fp32 in/out.
// R14: attn = R10 4-wave structure (2 waves/SIMD TLP -- R13's 1 wave/SIMD
//      regressed to 53us, latency-serialized) with V moved OUT of LDS the
//      RIGHT way: qkv's V epilogue stores V in MFMA-fragment order
//      [bh][chunk][kc][nt][lane][8] so attn's V loads are base+lane*16B --
//      one coalesced 1KB transaction per instr, L1-served (R11's 43->72us
//      failure was 16-line-per-instr scatter, not the reg-V concept).
//      K stays LDS-staged (4-deep, 32KB, swizzled). LDS reads/chunk/CU drop
//      ~1550->~800cy; max pipe = MFMA 1242. Schedule = R11's proven counted
//      vmcnt skeleton (10 ops/region) + exp||qk||pv fused region. GEMMs=R6.
// ---------------------------------------------------------------------------

using bf16   = __bf16;
using bf16x8 = __attribute__((ext_vector_type(8))) __bf16;
using bf16x4 = __attribute__((ext_vector_type(4))) __bf16;
using f32x4  = __attribute__((ext_vector_type(4))) float;

#define MFMA16(a, b, c) __builtin_amdgcn_mfma_f32_16x16x32_bf16((a), (b), (c), 0, 0, 0)
#define WAIT_VM0() asm volatile("s_waitcnt vmcnt(0)" ::: "memory")
#define WAITBAR(N) asm volatile("s_waitcnt vmcnt(" #N ")\n\ts_barrier" ::: "memory")

__device__ __forceinline__ bf16x8 ld8(const bf16* p) { return *(const bf16x8*)p; }

// async global->LDS, 16B/lane; lds_base is wave-uniform, HW adds lane*16.
__device__ __forceinline__ void ldg_lds16(bf16* lds_base, const bf16* g) {
    __builtin_amdgcn_global_load_lds(
        (const __attribute__((address_space(1))) void*)g,
        (__attribute__((address_space(3))) void*)lds_base, 16, 0, 0);
}

__device__ __forceinline__ float fast_exp2(float x) {
#if __has_builtin(__builtin_amdgcn_exp2f)
    return __builtin_amdgcn_exp2f(x);
#else
    return exp2f(x);
#endif
}

// ---------------------------------------------------------------------------
// Merged prep: z=0..3 transpose+convert W*; z=4 convert x -> bf16.
// ---------------------------------------------------------------------------
__global__ __launch_bounds__(256) void prep_kernel(
    const float* __restrict__ x, const float* __restrict__ Wq,
    const float* __restrict__ Wk, const float* __restrict__ Wv,
    const float* __restrict__ Wo, bf16* __restrict__ xb,
    bf16* __restrict__ WtBase) {
    const int z = blockIdx.z;
    const int tid = threadIdx.x;
    if (z == 4) {
        int id = blockIdx.y * 32 + blockIdx.x;      // 0..1023
#pragma unroll
        for (int k = 0; k < 4; ++k) {
            int i = id * 4096 + k * 1024 + tid * 4;
            float4 v = *(const float4*)&x[i];
            bf16x4 o = { (bf16)v.x, (bf16)v.y, (bf16)v.z, (bf16)v.w };
            *(bf16x4*)&xb[i] = o;
        }
        return;
    }
    __shared__ float tile[32][33];
    const float* W = (z == 0) ? Wq : (z == 1) ? Wk : (z == 2) ? Wv : Wo;
    bf16* Wt = WtBase + (size_t)z * 1024 * 1024;
    const int tx = tid & 31, ty = tid >> 5;          // 32 x 8
    const int x0 = blockIdx.x * 32, y0 = blockIdx.y * 32;
#pragma unroll
    for (int i = 0; i < 4; ++i)
        tile[ty + i * 8][tx] = W[(size_t)(y0 + ty + i * 8) * 1024 + x0 + tx];
    __syncthreads();
#pragma unroll
    for (int i = 0; i < 4; ++i)
        Wt[(size_t)(x0 + ty + i * 8) * 1024 + y0 + tx] = (bf16)tile[tx][ty + i * 8];
}

// ---------------------------------------------------------------------------
// 128x128 GEMM core, async double-buffered (R6 exact).
// ---------------------------------------------------------------------------
__device__ __forceinline__ void gemm_stage(const bf16* __restrict__ src, int r0,
                                           int k0, bf16* dst, int w, int lane) {
#pragma unroll
    for (int c = 0; c < 2; ++c) {
        int flat = (w * 2 + c) * 64 + lane;
        int row = flat >> 2, cc = flat & 3;
        int gk = (cc ^ ((row >> 1) & 3)) * 8;
        ldg_lds16(dst + (size_t)(w * 2 + c) * 512,
                  src + (size_t)(r0 + row) * 1024 + k0 + gk);
    }
}

__device__ __forceinline__ void gemm_core_128(const bf16* __restrict__ A,
                                              const bf16* __restrict__ Bt,
                                              int m0, int n0,
                                              bf16* As, bf16* Bs,   // each 2*4096
                                              f32x4 (&acc)[4][4]) {
    const int tid = threadIdx.x, lane = tid & 63, w = tid >> 6;
    const int lo = lane & 15, quad = lane >> 4;
    const int wm = w >> 1, wn = w & 1;

    gemm_stage(A,  m0, 0, As, w, lane);
    gemm_stage(Bt, n0, 0, Bs, w, lane);
    WAIT_VM0();
    __syncthreads();

    for (int it = 0; it < 32; ++it) {
        const int buf = it & 1;
        if (it + 1 < 32) {
            gemm_stage(A,  m0, (it + 1) * 32, As + (buf ^ 1) * 4096, w, lane);
            gemm_stage(Bt, n0, (it + 1) * 32, Bs + (buf ^ 1) * 4096, w, lane);
        }
        const bf16* Ab = As + buf * 4096;
        const bf16* Bb = Bs + buf * 4096;
        bf16x8 af[4], bq[4];
#pragma unroll
        for (int t = 0; t < 4; ++t) {
            int r = wm * 64 + t * 16 + lo;
            af[t] = ld8(&Ab[r * 32 + ((quad ^ ((r >> 1) & 3)) * 8)]);
        }
#pragma unroll
        for (int t = 0; t < 4; ++t) {
            int r = wn * 64 + t * 16 + lo;
            bq[t] = ld8(&Bb[r * 32 + ((quad ^ ((r >> 1) & 3)) * 8)]);
        }
#pragma unroll
        for (int mt = 0; mt < 4; ++mt)
#pragma unroll
            for (int nt = 0; nt < 4; ++nt)
                acc[mt][nt] = MFMA16(af[mt], bq[nt], acc[mt][nt]);
        WAIT_VM0();
        __syncthreads();
    }
}

// Fused QKV projection. z=0 -> Q (scaled log2e/8), z=1 -> K, z=2 -> V in
// MFMA-fragment order Vf[bh][c=s/64][kc][nt][qd*16+lo][e] via LDS-transpose
// epilogue (destination-major loop keeps global writes coalesced). The key
// permutation slot = qd*8 + T*4 + o <-> key = T*16 + qd*4 + o is folded in.
__global__ __launch_bounds__(256, 3) void qkv_gemm_kernel(
    const bf16* __restrict__ Xb, const bf16* __restrict__ Wts,
    const float* __restrict__ bq, const float* __restrict__ bk,
    const float* __restrict__ bv,
    bf16* __restrict__ Qo, bf16* __restrict__ Ko, bf16* __restrict__ Vto) {
    __shared__ bf16 Smem[4 * 4096];
    bf16* As = Smem;
    bf16* Bs = Smem + 2 * 4096;
    const int z = blockIdx.z;
    const bf16*  Bt   = Wts + (size_t)z * 1024 * 1024;
    const float* bias = (z == 0) ? bq : (z == 1) ? bk : bv;
    const int m0 = blockIdx.y * 128, n0 = blockIdx.x * 128;

    f32x4 acc[4][4] = {};
    gemm_core_128(Xb, Bt, m0, n0, As, Bs, acc);

    const int tid = threadIdx.x;
    const int lane = tid & 63, w = tid >> 6;
    const int lo = lane & 15, quad = lane >> 4;
    const int wm = w >> 1, wn = w & 1;
    const float QSCALE = 0.125f * 1.44269504088896f;  // 1/sqrt(64) * log2(e)

    if (z == 2) {
        // ---- V: transpose via LDS (two 128n x 64m half-tiles, stride 68),
        //      then write in attn fragment order, destination-major. ----
        bf16* T = Smem;                      // 128*68 = 8704 elems
        const int b = m0 >> 11;
        const int s_base = m0 & 2047;
        const int h0 = n0 >> 6;
#pragma unroll
        for (int half = 0; half < 2; ++half) {
            __syncthreads();
            if (wm == half) {
#pragma unroll
                for (int nt = 0; nt < 4; ++nt)
#pragma unroll
                    for (int mt = 0; mt < 4; ++mt)
#pragma unroll
                        for (int r = 0; r < 4; ++r) {
                            int nn = wn * 64 + nt * 16 + lo;
                            int mm = mt * 16 + quad * 4 + r;
                            T[nn * 68 + mm] = (bf16)(acc[mt][nt][r] + bias[n0 + nn]);
                        }
            }
            __syncthreads();
            const int c = (s_base >> 6) + half;   // 64-key chunk index
#pragma unroll
            for (int p = 0; p < 8; ++p) {
                int d = p * 1024 + tid * 4;       // dest elem (4-aligned)
                int e   = d & 7;                  // e base (0 or 4)
                int lo2 = (d >> 3) & 15;
                int qd  = (d >> 7) & 3;
                int nt  = (d >> 9) & 3;
                int kc  = (d >> 11) & 1;
                int hh  = d >> 12;                // 0/1: head within block
                int j = kc * 32 + qd * 8 + e;     // within-chunk slot index
                // inverse of the slot<->key permutation (colp)
                int col = (j & 32) | (((j >> 3) & 3) << 2)
                        | (((j >> 2) & 1) << 4) | (j & 3);
                int row = hh * 64 + nt * 16 + lo2;
                bf16x4 v = *(const bf16x4*)&T[row * 68 + col];
                *(bf16x4*)&Vto[((size_t)(b * 16 + h0 + hh) << 17)
                               + (size_t)((((c * 2 + kc) * 4 + nt) << 9)
                                          + (qd * 16 + lo2) * 8 + e)] = v;
            }
        }
    } else {
#pragma unroll
        for (int mt = 0; mt < 4; ++mt)
#pragma unroll
            for (int nt = 0; nt < 4; ++nt)
#pragma unroll
                for (int r = 0; r < 4; ++r) {
                    int m = m0 + wm * 64 + mt * 16 + quad * 4 + r;
                    int n = n0 + wn * 64 + nt * 16 + lo;
                    float v = acc[mt][nt][r] + bias[n];
                    int b = m >> 11, s = m & 2047, h = n >> 6, hd = n & 63;
                    if (z == 0)
                        Qo[((size_t)((b * 16 + h) * 2048 + s) << 6) + hd] = (bf16)(v * QSCALE);
                    else
                        Ko[((size_t)((b * 16 + h) * 2048 + s) << 6) + hd] = (bf16)v;
                }
    }
}

// ---------------------------------------------------------------------------
// Output projection, 64x128 tiles (512 blocks = 2/CU), double-buffered (R6).
// ---------------------------------------------------------------------------
__global__ __launch_bounds__(256, 2) void out_gemm_kernel(
    const bf16* __restrict__ A, const bf16* __restrict__ Bt,
    const float* __restrict__ bo, float* __restrict__ Co) {
    __shared__ bf16 As[2 * 2048];
    __shared__ bf16 Bs[2 * 4096];
    const int tid = threadIdx.x, lane = tid & 63, w = tid >> 6;
    const int lo = lane & 15, quad = lane >> 4;
    const int wm = w >> 1, wn = w & 1;
    const int m0 = blockIdx.y * 64, n0 = blockIdx.x * 128;

    auto stageA = [&](int k0, bf16* dst) {
        int flat = w * 64 + lane;
        int row = flat >> 2, cc = flat & 3;
        int gk = (cc ^ ((row >> 1) & 3)) * 8;
        ldg_lds16(dst + (size_t)w * 512, A + (size_t)(m0 + row) * 1024 + k0 + gk);
    };
    auto stageB = [&](int k0, bf16* dst) {
#pragma unroll
        for (int c = 0; c < 2; ++c) {
            int flat = (w * 2 + c) * 64 + lane;
            int row = flat >> 2, cc = flat & 3;
            int gk = (cc ^ ((row >> 1) & 3)) * 8;
            ldg_lds16(dst + (size_t)(w * 2 + c) * 512,
                      Bt + (size_t)(n0 + row) * 1024 + k0 + gk);
        }
    };

    f32x4 acc[2][4] = {};
    stageA(0, As);
    stageB(0, Bs);
    WAIT_VM0();
    __syncthreads();

    for (int it = 0; it < 32; ++it) {
        const int buf = it & 1;
        if (it + 1 < 32) {
            stageA((it + 1) * 32, As + (buf ^ 1) * 2048);
            stageB((it + 1) * 32, Bs + (buf ^ 1) * 4096);
        }
        const bf16* Ab = As + buf * 2048;
        const bf16* Bb = Bs + buf * 4096;
        bf16x8 af[2], bq[4];
#pragma unroll
        for (int t = 0; t < 2; ++t) {
            int r = wm * 32 + t * 16 + lo;
            af[t] = ld8(&Ab[r * 32 + ((quad ^ ((r >> 1) & 3)) * 8)]);
        }
#pragma unroll
        for (int t = 0; t < 4; ++t) {
            int r = wn * 64 + t * 16 + lo;
            bq[t] = ld8(&Bb[r * 32 + ((quad ^ ((r >> 1) & 3)) * 8)]);
        }
#pragma unroll
        for (int mt = 0; mt < 2; ++mt)
#pragma unroll
            for (int nt = 0; nt < 4; ++nt)
                acc[mt][nt] = MFMA16(af[mt], bq[nt], acc[mt][nt]);
        WAIT_VM0();
        __syncthreads();
    }

#pragma unroll
    for (int mt = 0; mt < 2; ++mt)
#pragma unroll
        for (int nt = 0; nt < 4; ++nt)
#pragma unroll
            for (int r = 0; r < 4; ++r) {
                int m = m0 + wm * 32 + mt * 16 + quad * 4 + r;
                int n = n0 + wn * 64 + nt * 16 + lo;
                Co[(size_t)m * 1024 + n] = acc[mt][nt][r] + bo[n];
            }
}

// ---------------------------------------------------------------------------
// Flash attention R14: S^T formulation, K via LDS, V via fragment-ordered
// global loads. Grid 512 x 256 (4 waves, 2 blk/CU = 2 waves/SIMD). Block =
// 128 q-rows of one (b,h); each wave owns 32 q. 64-key chunks.
//   K: 4-deep LDS (32KB), staged 2 ahead, swizzled; 2 ldg_lds/wave/chunk.
//   V: Vf[bh][c][kc][nt][lane][8] -- load = base + lane*16B, one coalesced
//      1KB transaction per instr, L1-served (4 waves share 8KB/chunk).
//      Double-buffered in regs one region ahead (VA/VB, 8 dwordx4/chunk).
// Region = exactly 10 vm ops (8 V + 2 K) -> counted WAITBAR(10) retires the
// whole previous region regardless of in-region reordering.
// Per-step single scheduling region: exp(S_i) || qk(i+1) || pv(V_i).
// ---------------------------------------------------------------------------
__global__ __launch_bounds__(256, 2) void attn_kernel(
    const bf16* __restrict__ Q, const bf16* __restrict__ K,
    const bf16* __restrict__ Vf, bf16* __restrict__ AO) {
    __shared__ bf16 Ks[4][64 * 64];
    const int tid = threadIdx.x, w = tid >> 6, lane = tid & 63;
    const int lo = lane & 15, quad = lane >> 4;
    const int blk = blockIdx.x;
    const int bh = (blk & 7) | ((blk >> 7) << 3);  // same-head -> same XCD
    const int qb = (blk >> 3) & 15;
    const int q0 = qb * 128 + w * 32;

    const bf16* Qb = Q + ((size_t)bh * 2048 + q0) * 64;
    const bf16* Kb = K + (size_t)bh * 2048 * 64;
    const bf16* Vlane = Vf + ((size_t)bh << 17) + lane * 8;

    // Q B-fragments: n-row = qt*16+lo, k = ks*32+quad*8
    bf16x8 qa[2][2];
#pragma unroll
    for (int qt = 0; qt < 2; ++qt)
#pragma unroll
        for (int ks = 0; ks < 2; ++ks)
            qa[qt][ks] = ld8(&Qb[(qt * 16 + lo) * 64 + ks * 32 + quad * 8]);

    f32x4 O[2][4] = {};
    float l_acc[2] = { 0.f, 0.f };

    // stage one 64-key K chunk (2 ldg_lds/wave); swizzle s(row)=row&7.
    auto stageK = [&](int s0, int buf) {
#pragma unroll
        for (int c = 0; c < 2; ++c) {
            int flat = (w * 2 + c) * 64 + lane;
            int row = flat >> 3, cc = flat & 7;
            int g = (cc ^ (row & 7)) * 8;
            ldg_lds16(&Ks[buf][(w * 2 + c) * 512], &Kb[(size_t)(s0 + row) * 64 + g]);
        }
    };

    // load V frags for chunk c into regs (8 coalesced global_load_dwordx4)
    auto vload = [&](int c, bf16x8 (&Vr)[2][4]) {
        const bf16* p = Vlane + ((size_t)c << 12);
#pragma unroll
        for (int kc = 0; kc < 2; ++kc)
#pragma unroll
            for (int nt = 0; nt < 4; ++nt)
                Vr[kc][nt] = ld8(p + ((kc * 4 + nt) << 9));
    };

    const int swz = lo & 7;  // read-side swizzle for K rows t*16+lo

    // ---- S^T = K * Q^T from Ks[nb] : 4 key m-tiles x 2 q n-tiles x 2 k ----
    auto qk = [&](int nb, f32x4 (&S)[2][4]) {
        const bf16* Kt = &Ks[nb][0];
#pragma unroll
        for (int qt = 0; qt < 2; ++qt)
#pragma unroll
            for (int t = 0; t < 4; ++t)
                S[qt][t] = f32x4{ 0.f, 0.f, 0.f, 0.f };
#pragma unroll
        for (int t = 0; t < 4; ++t) {
            int r = t * 16 + lo;
#pragma unroll
            for (int ks = 0; ks < 2; ++ks) {
                bf16x8 kf = ld8(&Kt[r * 64 + (((quad + 4 * ks) ^ swz) * 8)]);
                S[0][t] = MFMA16(kf, qa[0][ks], S[0][t]);
                S[1][t] = MFMA16(kf, qa[1][ks], S[1][t]);
            }
        }
    };

    // ---- exp(Sin) -> pa (PV A-frags, keys slot-permuted) + l_acc ----
    auto expP = [&](f32x4 (&Sin)[2][4], bf16x8 (&pa)[2][2]) {
#pragma unroll
        for (int qt = 0; qt < 2; ++qt)
#pragma unroll
            for (int kc = 0; kc < 2; ++kc) {
                float e0 = fast_exp2(Sin[qt][2 * kc][0]);
                float e1 = fast_exp2(Sin[qt][2 * kc][1]);
                float e2 = fast_exp2(Sin[qt][2 * kc][2]);
                float e3 = fast_exp2(Sin[qt][2 * kc][3]);
                float e4 = fast_exp2(Sin[qt][2 * kc + 1][0]);
                float e5 = fast_exp2(Sin[qt][2 * kc + 1][1]);
                float e6 = fast_exp2(Sin[qt][2 * kc + 1][2]);
                float e7 = fast_exp2(Sin[qt][2 * kc + 1][3]);
                l_acc[qt] += ((e0 + e1) + (e2 + e3)) + ((e4 + e5) + (e6 + e7));
                pa[qt][kc] = bf16x8{ (bf16)e0, (bf16)e1, (bf16)e2, (bf16)e3,
                                     (bf16)e4, (bf16)e5, (bf16)e6, (bf16)e7 };
            }
    };

    // ---- PV from register V frags ----
    auto pv = [&](bf16x8 (&Vr)[2][4], bf16x8 (&pa)[2][2]) {
#pragma unroll
        for (int kc = 0; kc < 2; ++kc)
#pragma unroll
            for (int nt = 0; nt < 4; ++nt) {
                O[0][nt] = MFMA16(pa[0][kc], Vr[kc][nt], O[0][nt]);
                O[1][nt] = MFMA16(pa[1][kc], Vr[kc][nt], O[1][nt]);
            }
    };

    // step i: exp(S_i) || S_{i+1}=qk || O+=P_i*V_i  (one region, no barrier)
    auto step = [&](f32x4 (&Sin)[2][4], f32x4 (&Sout)[2][4], int nb,
                    bf16x8 (&Vr)[2][4]) {
        bf16x8 pa[2][2];
        expP(Sin, pa);
        qk(nb, Sout);
        pv(Vr, pa);
    };

    bf16x8 VA[2][4], VB[2][4];
    vload(0, VB);                   // V(0)
    stageK(0, 0);
    stageK(64, 1);
    WAITBAR(0);                     // drain once: K0,K1 staged, V0 in regs

    f32x4 Sa[2][4], Sb[2][4];
    qk(0, Sa);

    for (int it = 0; it < 30; it += 2) {
        // step it (even): consume VB=V(it), load VA=V(it+1)
        vload(it + 1, VA);
        stageK((it + 2) * 64, (it + 2) & 3);
        WAITBAR(10);                // retires prev region: K(it+1) + V(it)
        step(Sa, Sb, (it + 1) & 3, VB);
        // step it+1 (odd): consume VA, load VB=V(it+2)
        vload(it + 2, VB);
        stageK((it + 3) * 64, (it + 3) & 3);
        WAITBAR(10);                // retires prev region: K(it+2) + V(it+1)
        step(Sb, Sa, (it + 2) & 3, VA);
    }
    // step 30: consume VB=V(30), load VA=V(31); K(31) staged last iter
    vload(31, VA);
    WAITBAR(8);                     // retires {V(30)x8, K(31)x2}
    step(Sa, Sb, 3, VB);            // exp(S30) || qk(31) || PV(30)
    // step 31: no loads left
    WAIT_VM0();                     // V(31) in regs
    {
        bf16x8 pa[2][2];
        expP(Sb, pa);
        pv(VA, pa);
    }

    // ---- epilogue: l lives at q=lo; redistribute to C-rows via shfl ----
    const int bb = bh >> 4, h = bh & 15;
#pragma unroll
    for (int qt = 0; qt < 2; ++qt) {
        float lt = l_acc[qt];
        lt += __shfl_xor(lt, 16, 64);
        lt += __shfl_xor(lt, 32, 64);   // total l for q = qt*16 + lo
        const size_t outbase = ((size_t)(bb * 2048 + q0 + qt * 16)) * 1024 + h * 64;
#pragma unroll
        for (int r = 0; r < 4; ++r) {
            float rl = 1.0f / __shfl(lt, quad * 4 + r, 64);
            size_t rowoff = outbase + (size_t)(quad * 4 + r) * 1024;
#pragma unroll
            for (int nt = 0; nt < 4; ++nt)
                AO[rowoff + nt * 16 + lo] = (bf16)(O[qt][nt][r] * rl);
        }
    }
}

// ---------------------------------------------------------------------------
extern "C" void kernel_launch(void* const* d_in, const int* in_sizes, int n_in,
                              void* d_out, int out_size, void* d_ws, size_t ws_size,
                              hipStream_t stream) {
    const float* x  = (const float*)d_in[0];
    const float* Wq = (const float*)d_in[1];
    const float* bq = (const float*)d_in[2];
    const float* Wk = (const float*)d_in[3];
    const float* bk = (const float*)d_in[4];
    const float* Wv = (const float*)d_in[5];
    const float* bv = (const float*)d_in[6];
    const float* Wo = (const float*)d_in[7];
    const float* bo = (const float*)d_in[8];
    float* out = (float*)d_out;

    bf16* wsb = (bf16*)d_ws;
    const size_t M1 = 1024u * 1024u;
    bf16* Xb  = wsb;
    bf16* AO  = wsb;            // aliases Xb (Xb dead after qkv_gemm)
    bf16* Wt  = wsb + 4 * M1;
    bf16* Qw  = wsb + 8 * M1;
    bf16* Kw  = wsb + 12 * M1;
    bf16* Vtw = wsb + 16 * M1;

    prep_kernel<<<dim3(32, 32, 5), 256, 0, stream>>>(x, Wq, Wk, Wv, Wo, Xb, Wt);
    qkv_gemm_kernel<<<dim3(8, 32, 3), 256, 0, stream>>>(Xb, Wt, bq, bk, bv, Qw, Kw, Vtw);
    attn_kernel<<<512, 256, 0, stream>>>(Qw, Kw, Vtw, AO);
    out_gemm_kernel<<<dim3(8, 64), 256, 0, stream>>>(AO, Wt + 3 * M1, bo, out);
}

// Round 6
// 181.289 us; speedup vs baseline: 1.1343x; 1.0059x over previous
//
#include <hip/hip_runtime.h>
#include <math.h>

// ---------------------------------------------------------------------------
// multi_head_attention: B=2, S=2048, D=1024, H=16, Hd=64, fp32 in/out.
// R15: attn de-phased. R10/R14 showed traffic moves (LDS halved, V coalesced)
//      change nothing: MfmaUtil ~28 / VALUBusy ~34 / ~38% dual-idle is a
//      PHASE-LOCK signature -- 4-wave blocks barrier-sync every chunk, so
//      co-SIMD waves hit VALU together then MFMA together (m114 inverse).
//      Fix: 2-wave blocks (grid 1024 x 128thr, 64 q/block), 4 blocks/CU with
//      INDEPENDENT barriers -> co-SIMD waves from different blocks drift,
//      exp-phase overlaps MFMA-phase. + T5 setprio(1) around MFMA clusters
//      (pays only with de-phased waves: m191 +4-7%, m190 null lockstep).
//      Data paths = R14 verified: K 4-deep LDS swizzled; V fragment-ordered
//      global regs; counted WAITBAR(12)/region. GEMMs = R6 exact.
// ---------------------------------------------------------------------------

using bf16   = __bf16;
using bf16x8 = __attribute__((ext_vector_type(8))) __bf16;
using bf16x4 = __attribute__((ext_vector_type(4))) __bf16;
using f32x4  = __attribute__((ext_vector_type(4))) float;

#define MFMA16(a, b, c) __builtin_amdgcn_mfma_f32_16x16x32_bf16((a), (b), (c), 0, 0, 0)
#define WAIT_VM0() asm volatile("s_waitcnt vmcnt(0)" ::: "memory")
#define WAITBAR(N) asm volatile("s_waitcnt vmcnt(" #N ")\n\ts_barrier" ::: "memory")

__device__ __forceinline__ bf16x8 ld8(const bf16* p) { return *(const bf16x8*)p; }

// async global->LDS, 16B/lane; lds_base is wave-uniform, HW adds lane*16.
__device__ __forceinline__ void ldg_lds16(bf16* lds_base, const bf16* g) {
    __builtin_amdgcn_global_load_lds(
        (const __attribute__((address_space(1))) void*)g,
        (__attribute__((address_space(3))) void*)lds_base, 16, 0, 0);
}

__device__ __forceinline__ float fast_exp2(float x) {
#if __has_builtin(__builtin_amdgcn_exp2f)
    return __builtin_amdgcn_exp2f(x);
#else
    return exp2f(x);
#endif
}

// ---------------------------------------------------------------------------
// Merged prep: z=0..3 transpose+convert W*; z=4 convert x -> bf16.
// ---------------------------------------------------------------------------
__global__ __launch_bounds__(256) void prep_kernel(
    const float* __restrict__ x, const float* __restrict__ Wq,
    const float* __restrict__ Wk, const float* __restrict__ Wv,
    const float* __restrict__ Wo, bf16* __restrict__ xb,
    bf16* __restrict__ WtBase) {
    const int z = blockIdx.z;
    const int tid = threadIdx.x;
    if (z == 4) {
        int id = blockIdx.y * 32 + blockIdx.x;      // 0..1023
#pragma unroll
        for (int k = 0; k < 4; ++k) {
            int i = id * 4096 + k * 1024 + tid * 4;
            float4 v = *(const float4*)&x[i];
            bf16x4 o = { (bf16)v.x, (bf16)v.y, (bf16)v.z, (bf16)v.w };
            *(bf16x4*)&xb[i] = o;
        }
        return;
    }
    __shared__ float tile[32][33];
    const float* W = (z == 0) ? Wq : (z == 1) ? Wk : (z == 2) ? Wv : Wo;
    bf16* Wt = WtBase + (size_t)z * 1024 * 1024;
    const int tx = tid & 31, ty = tid >> 5;          // 32 x 8
    const int x0 = blockIdx.x * 32, y0 = blockIdx.y * 32;
#pragma unroll
    for (int i = 0; i < 4; ++i)
        tile[ty + i * 8][tx] = W[(size_t)(y0 + ty + i * 8) * 1024 + x0 + tx];
    __syncthreads();
#pragma unroll
    for (int i = 0; i < 4; ++i)
        Wt[(size_t)(x0 + ty + i * 8) * 1024 + y0 + tx] = (bf16)tile[tx][ty + i * 8];
}

// ---------------------------------------------------------------------------
// 128x128 GEMM core, async double-buffered (R6 exact).
// ---------------------------------------------------------------------------
__device__ __forceinline__ void gemm_stage(const bf16* __restrict__ src, int r0,
                                           int k0, bf16* dst, int w, int lane) {
#pragma unroll
    for (int c = 0; c < 2; ++c) {
        int flat = (w * 2 + c) * 64 + lane;
        int row = flat >> 2, cc = flat & 3;
        int gk = (cc ^ ((row >> 1) & 3)) * 8;
        ldg_lds16(dst + (size_t)(w * 2 + c) * 512,
                  src + (size_t)(r0 + row) * 1024 + k0 + gk);
    }
}

__device__ __forceinline__ void gemm_core_128(const bf16* __restrict__ A,
                                              const bf16* __restrict__ Bt,
                                              int m0, int n0,
                                              bf16* As, bf16* Bs,   // each 2*4096
                                              f32x4 (&acc)[4][4]) {
    const int tid = threadIdx.x, lane = tid & 63, w = tid >> 6;
    const int lo = lane & 15, quad = lane >> 4;
    const int wm = w >> 1, wn = w & 1;

    gemm_stage(A,  m0, 0, As, w, lane);
    gemm_stage(Bt, n0, 0, Bs, w, lane);
    WAIT_VM0();
    __syncthreads();

    for (int it = 0; it < 32; ++it) {
        const int buf = it & 1;
        if (it + 1 < 32) {
            gemm_stage(A,  m0, (it + 1) * 32, As + (buf ^ 1) * 4096, w, lane);
            gemm_stage(Bt, n0, (it + 1) * 32, Bs + (buf ^ 1) * 4096, w, lane);
        }
        const bf16* Ab = As + buf * 4096;
        const bf16* Bb = Bs + buf * 4096;
        bf16x8 af[4], bq[4];
#pragma unroll
        for (int t = 0; t < 4; ++t) {
            int r = wm * 64 + t * 16 + lo;
            af[t] = ld8(&Ab[r * 32 + ((quad ^ ((r >> 1) & 3)) * 8)]);
        }
#pragma unroll
        for (int t = 0; t < 4; ++t) {
            int r = wn * 64 + t * 16 + lo;
            bq[t] = ld8(&Bb[r * 32 + ((quad ^ ((r >> 1) & 3)) * 8)]);
        }
#pragma unroll
        for (int mt = 0; mt < 4; ++mt)
#pragma unroll
            for (int nt = 0; nt < 4; ++nt)
                acc[mt][nt] = MFMA16(af[mt], bq[nt], acc[mt][nt]);
        WAIT_VM0();
        __syncthreads();
    }
}

// Fused QKV projection. z=0 -> Q (scaled log2e/8), z=1 -> K, z=2 -> V in
// MFMA-fragment order Vf[bh][c=s/64][kc][nt][qd*16+lo][e] via LDS-transpose
// epilogue (destination-major loop keeps global writes coalesced). The key
// permutation slot = qd*8 + T*4 + o <-> key = T*16 + qd*4 + o is folded in.
__global__ __launch_bounds__(256, 3) void qkv_gemm_kernel(
    const bf16* __restrict__ Xb, const bf16* __restrict__ Wts,
    const float* __restrict__ bq, const float* __restrict__ bk,
    const float* __restrict__ bv,
    bf16* __restrict__ Qo, bf16* __restrict__ Ko, bf16* __restrict__ Vto) {
    __shared__ bf16 Smem[4 * 4096];
    bf16* As = Smem;
    bf16* Bs = Smem + 2 * 4096;
    const int z = blockIdx.z;
    const bf16*  Bt   = Wts + (size_t)z * 1024 * 1024;
    const float* bias = (z == 0) ? bq : (z == 1) ? bk : bv;
    const int m0 = blockIdx.y * 128, n0 = blockIdx.x * 128;

    f32x4 acc[4][4] = {};
    gemm_core_128(Xb, Bt, m0, n0, As, Bs, acc);

    const int tid = threadIdx.x;
    const int lane = tid & 63, w = tid >> 6;
    const int lo = lane & 15, quad = lane >> 4;
    const int wm = w >> 1, wn = w & 1;
    const float QSCALE = 0.125f * 1.44269504088896f;  // 1/sqrt(64) * log2(e)

    if (z == 2) {
        // ---- V: transpose via LDS (two 128n x 64m half-tiles, stride 68),
        //      then write in attn fragment order, destination-major. ----
        bf16* T = Smem;                      // 128*68 = 8704 elems
        const int b = m0 >> 11;
        const int s_base = m0 & 2047;
        const int h0 = n0 >> 6;
#pragma unroll
        for (int half = 0; half < 2; ++half) {
            __syncthreads();
            if (wm == half) {
#pragma unroll
                for (int nt = 0; nt < 4; ++nt)
#pragma unroll
                    for (int mt = 0; mt < 4; ++mt)
#pragma unroll
                        for (int r = 0; r < 4; ++r) {
                            int nn = wn * 64 + nt * 16 + lo;
                            int mm = mt * 16 + quad * 4 + r;
                            T[nn * 68 + mm] = (bf16)(acc[mt][nt][r] + bias[n0 + nn]);
                        }
            }
            __syncthreads();
            const int c = (s_base >> 6) + half;   // 64-key chunk index
#pragma unroll
            for (int p = 0; p < 8; ++p) {
                int d = p * 1024 + tid * 4;       // dest elem (4-aligned)
                int e   = d & 7;                  // e base (0 or 4)
                int lo2 = (d >> 3) & 15;
                int qd  = (d >> 7) & 3;
                int nt  = (d >> 9) & 3;
                int kc  = (d >> 11) & 1;
                int hh  = d >> 12;                // 0/1: head within block
                int j = kc * 32 + qd * 8 + e;     // within-chunk slot index
                // inverse of the slot<->key permutation (colp)
                int col = (j & 32) | (((j >> 3) & 3) << 2)
                        | (((j >> 2) & 1) << 4) | (j & 3);
                int row = hh * 64 + nt * 16 + lo2;
                bf16x4 v = *(const bf16x4*)&T[row * 68 + col];
                *(bf16x4*)&Vto[((size_t)(b * 16 + h0 + hh) << 17)
                               + (size_t)((((c * 2 + kc) * 4 + nt) << 9)
                                          + (qd * 16 + lo2) * 8 + e)] = v;
            }
        }
    } else {
#pragma unroll
        for (int mt = 0; mt < 4; ++mt)
#pragma unroll
            for (int nt = 0; nt < 4; ++nt)
#pragma unroll
                for (int r = 0; r < 4; ++r) {
                    int m = m0 + wm * 64 + mt * 16 + quad * 4 + r;
                    int n = n0 + wn * 64 + nt * 16 + lo;
                    float v = acc[mt][nt][r] + bias[n];
                    int b = m >> 11, s = m & 2047, h = n >> 6, hd = n & 63;
                    if (z == 0)
                        Qo[((size_t)((b * 16 + h) * 2048 + s) << 6) + hd] = (bf16)(v * QSCALE);
                    else
                        Ko[((size_t)((b * 16 + h) * 2048 + s) << 6) + hd] = (bf16)v;
                }
    }
}

// ---------------------------------------------------------------------------
// Output projection, 64x128 tiles (512 blocks = 2/CU), double-buffered (R6).
// ---------------------------------------------------------------------------
__global__ __launch_bounds__(256, 2) void out_gemm_kernel(
    const bf16* __restrict__ A, const bf16* __restrict__ Bt,
    const float* __restrict__ bo, float* __restrict__ Co) {
    __shared__ bf16 As[2 * 2048];
    __shared__ bf16 Bs[2 * 4096];
    const int tid = threadIdx.x, lane = tid & 63, w = tid >> 6;
    const int lo = lane & 15, quad = lane >> 4;
    const int wm = w >> 1, wn = w & 1;
    const int m0 = blockIdx.y * 64, n0 = blockIdx.x * 128;

    auto stageA = [&](int k0, bf16* dst) {
        int flat = w * 64 + lane;
        int row = flat >> 2, cc = flat & 3;
        int gk = (cc ^ ((row >> 1) & 3)) * 8;
        ldg_lds16(dst + (size_t)w * 512, A + (size_t)(m0 + row) * 1024 + k0 + gk);
    };
    auto stageB = [&](int k0, bf16* dst) {
#pragma unroll
        for (int c = 0; c < 2; ++c) {
            int flat = (w * 2 + c) * 64 + lane;
            int row = flat >> 2, cc = flat & 3;
            int gk = (cc ^ ((row >> 1) & 3)) * 8;
            ldg_lds16(dst + (size_t)(w * 2 + c) * 512,
                      Bt + (size_t)(n0 + row) * 1024 + k0 + gk);
        }
    };

    f32x4 acc[2][4] = {};
    stageA(0, As);
    stageB(0, Bs);
    WAIT_VM0();
    __syncthreads();

    for (int it = 0; it < 32; ++it) {
        const int buf = it & 1;
        if (it + 1 < 32) {
            stageA((it + 1) * 32, As + (buf ^ 1) * 2048);
            stageB((it + 1) * 32, Bs + (buf ^ 1) * 4096);
        }
        const bf16* Ab = As + buf * 2048;
        const bf16* Bb = Bs + buf * 4096;
        bf16x8 af[2], bq[4];
#pragma unroll
        for (int t = 0; t < 2; ++t) {
            int r = wm * 32 + t * 16 + lo;
            af[t] = ld8(&Ab[r * 32 + ((quad ^ ((r >> 1) & 3)) * 8)]);
        }
#pragma unroll
        for (int t = 0; t < 4; ++t) {
            int r = wn * 64 + t * 16 + lo;
            bq[t] = ld8(&Bb[r * 32 + ((quad ^ ((r >> 1) & 3)) * 8)]);
        }
#pragma unroll
        for (int mt = 0; mt < 2; ++mt)
#pragma unroll
            for (int nt = 0; nt < 4; ++nt)
                acc[mt][nt] = MFMA16(af[mt], bq[nt], acc[mt][nt]);
        WAIT_VM0();
        __syncthreads();
    }

#pragma unroll
    for (int mt = 0; mt < 2; ++mt)
#pragma unroll
        for (int nt = 0; nt < 4; ++nt)
#pragma unroll
            for (int r = 0; r < 4; ++r) {
                int m = m0 + wm * 32 + mt * 16 + quad * 4 + r;
                int n = n0 + wn * 64 + nt * 16 + lo;
                Co[(size_t)m * 1024 + n] = acc[mt][nt][r] + bo[n];
            }
}

// ---------------------------------------------------------------------------
// Flash attention R15: S^T formulation, K via LDS, V via fragment-ordered
// global loads. Grid 1024 x 128 (2 waves/block, 64 q/block, 4 blocks/CU).
// Independent per-block barriers de-phase co-SIMD waves -> cross-wave
// MFMA/VALU overlap. Each wave owns 32 q. 64-key chunks.
//   K: 4-deep LDS (32KB), staged 2 ahead, swizzled; 4 ldg_lds/wave/chunk.
//   V: Vf[bh][c][kc][nt][lane][8] -- load = base + lane*16B, coalesced,
//      L1/L2-served. Double-buffered in regs one region ahead (VA/VB).
// Region = exactly 12 vm ops (8 V + 4 K) -> counted WAITBAR(12) retires the
// whole previous region regardless of in-region reordering.
// Per-step single scheduling region: exp(S_i) || qk(i+1) || pv(V_i), with
// s_setprio(1) around the MFMA clusters (T5; pays with de-phased waves).
// ---------------------------------------------------------------------------
__global__ __launch_bounds__(128, 2) void attn_kernel(
    const bf16* __restrict__ Q, const bf16* __restrict__ K,
    const bf16* __restrict__ Vf, bf16* __restrict__ AO) {
    __shared__ bf16 Ks[4][64 * 64];
    const int tid = threadIdx.x, w = tid >> 6, lane = tid & 63;
    const int lo = lane & 15, quad = lane >> 4;
    const int blk = blockIdx.x;
    // bijective: blk = (hi<<8)|(qb<<3)|lo3 ; bh = lo3|(hi<<3) keeps
    // same-head -> same XCD (blk%8 == lo3), qb = 0..31 (64-q blocks).
    const int bh = (blk & 7) | ((blk >> 8) << 3);
    const int qb = (blk >> 3) & 31;
    const int q0 = qb * 64 + w * 32;

    const bf16* Qb = Q + ((size_t)bh * 2048 + q0) * 64;
    const bf16* Kb = K + (size_t)bh * 2048 * 64;
    const bf16* Vlane = Vf + ((size_t)bh << 17) + lane * 8;

    // Q B-fragments: n-row = qt*16+lo, k = ks*32+quad*8
    bf16x8 qa[2][2];
#pragma unroll
    for (int qt = 0; qt < 2; ++qt)
#pragma unroll
        for (int ks = 0; ks < 2; ++ks)
            qa[qt][ks] = ld8(&Qb[(qt * 16 + lo) * 64 + ks * 32 + quad * 8]);

    f32x4 O[2][4] = {};
    float l_acc[2] = { 0.f, 0.f };

    // stage one 64-key K chunk (4 ldg_lds/wave, 2 waves cover 8 sections);
    // swizzle s(row)=row&7.
    auto stageK = [&](int s0, int buf) {
#pragma unroll
        for (int c = 0; c < 4; ++c) {
            int sc = w * 4 + c;                    // section 0..7
            int flat = sc * 64 + lane;
            int row = flat >> 3, cc = flat & 7;
            int g = (cc ^ (row & 7)) * 8;
            ldg_lds16(&Ks[buf][sc * 512], &Kb[(size_t)(s0 + row) * 64 + g]);
        }
    };

    // load V frags for chunk c into regs (8 coalesced global_load_dwordx4)
    auto vload = [&](int c, bf16x8 (&Vr)[2][4]) {
        const bf16* p = Vlane + ((size_t)c << 12);
#pragma unroll
        for (int kc = 0; kc < 2; ++kc)
#pragma unroll
            for (int nt = 0; nt < 4; ++nt)
                Vr[kc][nt] = ld8(p + ((kc * 4 + nt) << 9));
    };

    const int swz = lo & 7;  // read-side swizzle for K rows t*16+lo

    // ---- S^T = K * Q^T from Ks[nb] : 4 key m-tiles x 2 q n-tiles x 2 k ----
    auto qk = [&](int nb, f32x4 (&S)[2][4]) {
        const bf16* Kt = &Ks[nb][0];
#pragma unroll
        for (int qt = 0; qt < 2; ++qt)
#pragma unroll
            for (int t = 0; t < 4; ++t)
                S[qt][t] = f32x4{ 0.f, 0.f, 0.f, 0.f };
        __builtin_amdgcn_s_setprio(1);
#pragma unroll
        for (int t = 0; t < 4; ++t) {
            int r = t * 16 + lo;
#pragma unroll
            for (int ks = 0; ks < 2; ++ks) {
                bf16x8 kf = ld8(&Kt[r * 64 + (((quad + 4 * ks) ^ swz) * 8)]);
                S[0][t] = MFMA16(kf, qa[0][ks], S[0][t]);
                S[1][t] = MFMA16(kf, qa[1][ks], S[1][t]);
            }
        }
        __builtin_amdgcn_s_setprio(0);
    };

    // ---- exp(Sin) -> pa (PV A-frags, keys slot-permuted) + l_acc ----
    auto expP = [&](f32x4 (&Sin)[2][4], bf16x8 (&pa)[2][2]) {
#pragma unroll
        for (int qt = 0; qt < 2; ++qt)
#pragma unroll
            for (int kc = 0; kc < 2; ++kc) {
                float e0 = fast_exp2(Sin[qt][2 * kc][0]);
                float e1 = fast_exp2(Sin[qt][2 * kc][1]);
                float e2 = fast_exp2(Sin[qt][2 * kc][2]);
                float e3 = fast_exp2(Sin[qt][2 * kc][3]);
                float e4 = fast_exp2(Sin[qt][2 * kc + 1][0]);
                float e5 = fast_exp2(Sin[qt][2 * kc + 1][1]);
                float e6 = fast_exp2(Sin[qt][2 * kc + 1][2]);
                float e7 = fast_exp2(Sin[qt][2 * kc + 1][3]);
                l_acc[qt] += ((e0 + e1) + (e2 + e3)) + ((e4 + e5) + (e6 + e7));
                pa[qt][kc] = bf16x8{ (bf16)e0, (bf16)e1, (bf16)e2, (bf16)e3,
                                     (bf16)e4, (bf16)e5, (bf16)e6, (bf16)e7 };
            }
    };

    // ---- PV from register V frags ----
    auto pv = [&](bf16x8 (&Vr)[2][4], bf16x8 (&pa)[2][2]) {
        __builtin_amdgcn_s_setprio(1);
#pragma unroll
        for (int kc = 0; kc < 2; ++kc)
#pragma unroll
            for (int nt = 0; nt < 4; ++nt) {
                O[0][nt] = MFMA16(pa[0][kc], Vr[kc][nt], O[0][nt]);
                O[1][nt] = MFMA16(pa[1][kc], Vr[kc][nt], O[1][nt]);
            }
        __builtin_amdgcn_s_setprio(0);
    };

    // step i: exp(S_i) || S_{i+1}=qk || O+=P_i*V_i  (one region, no barrier)
    auto step = [&](f32x4 (&Sin)[2][4], f32x4 (&Sout)[2][4], int nb,
                    bf16x8 (&Vr)[2][4]) {
        bf16x8 pa[2][2];
        expP(Sin, pa);
        qk(nb, Sout);
        pv(Vr, pa);
    };

    bf16x8 VA[2][4], VB[2][4];
    vload(0, VB);                   // V(0)
    stageK(0, 0);
    stageK(64, 1);
    WAITBAR(0);                     // drain once: K0,K1 staged, V0 in regs

    f32x4 Sa[2][4], Sb[2][4];
    qk(0, Sa);

    for (int it = 0; it < 30; it += 2) {
        // step it (even): consume VB=V(it), load VA=V(it+1)
        vload(it + 1, VA);
        stageK((it + 2) * 64, (it + 2) & 3);
        WAITBAR(12);                // retires prev region: K(it+1) + V(it)
        step(Sa, Sb, (it + 1) & 3, VB);
        // step it+1 (odd): consume VA, load VB=V(it+2)
        vload(it + 2, VB);
        stageK((it + 3) * 64, (it + 3) & 3);
        WAITBAR(12);                // retires prev region: K(it+2) + V(it+1)
        step(Sb, Sa, (it + 2) & 3, VA);
    }
    // step 30: consume VB=V(30), load VA=V(31); K(31) staged last iter
    vload(31, VA);
    WAITBAR(8);                     // retires {V(30)x8, K(31)x4}
    step(Sa, Sb, 3, VB);            // exp(S30) || qk(31) || PV(30)
    // step 31: no loads left
    WAIT_VM0();                     // V(31) in regs
    {
        bf16x8 pa[2][2];
        expP(Sb, pa);
        pv(VA, pa);
    }

    // ---- epilogue: l lives at q=lo; redistribute to C-rows via shfl ----
    const int bb = bh >> 4, h = bh & 15;
#pragma unroll
    for (int qt = 0; qt < 2; ++qt) {
        float lt = l_acc[qt];
        lt += __shfl_xor(lt, 16, 64);
        lt += __shfl_xor(lt, 32, 64);   // total l for q = qt*16 + lo
        const size_t outbase = ((size_t)(bb * 2048 + q0 + qt * 16)) * 1024 + h * 64;
#pragma unroll
        for (int r = 0; r < 4; ++r) {
            float rl = 1.0f / __shfl(lt, quad * 4 + r, 64);
            size_t rowoff = outbase + (size_t)(quad * 4 + r) * 1024;
#pragma unroll
            for (int nt = 0; nt < 4; ++nt)
                AO[rowoff + nt * 16 + lo] = (bf16)(O[qt][nt][r] * rl);
        }
    }
}

// ---------------------------------------------------------------------------
extern "C" void kernel_launch(void* const* d_in, const int* in_sizes, int n_in,
                              void* d_out, int out_size, void* d_ws, size_t ws_size,
                              hipStream_t stream) {
    const float* x  = (const float*)d_in[0];
    const float* Wq = (const float*)d_in[1];
    const float* bq = (const float*)d_in[2];
    const float* Wk = (const float*)d_in[3];
    const float* bk = (const float*)d_in[4];
    const float* Wv = (const float*)d_in[5];
    const float* bv = (const float*)d_in[6];
    const float* Wo = (const float*)d_in[7];
    const float* bo = (const float*)d_in[8];
    float* out = (float*)d_out;

    bf16* wsb = (bf16*)d_ws;
    const size_t M1 = 1024u * 1024u;
    bf16* Xb  = wsb;
    bf16* AO  = wsb;            // aliases Xb (Xb dead after qkv_gemm)
    bf16* Wt  = wsb + 4 * M1;
    bf16* Qw  = wsb + 8 * M1;
    bf16* Kw  = wsb + 12 * M1;
    bf16* Vtw = wsb + 16 * M1;

    prep_kernel<<<dim3(32, 32, 5), 256, 0, stream>>>(x, Wq, Wk, Wv, Wo, Xb, Wt);
    qkv_gemm_kernel<<<dim3(8, 32, 3), 256, 0, stream>>>(Xb, Wt, bq, bk, bv, Qw, Kw, Vtw);
    attn_kernel<<<1024, 128, 0, stream>>>(Qw, Kw, Vtw, AO);
    out_gemm_kernel<<<dim3(8, 64), 256, 0, stream>>>(AO, Wt + 3 * M1, bo, out);
}

// Round 7
// 179.713 us; speedup vs baseline: 1.1442x; 1.0088x over previous
//
#include <hip/hip_runtime.h>
#include <math.h>

// ---------------------------------------------------------------------------
// multi_head_attention: B=2, S=2048, D=1024, H=16, Hd=64, fp32 in/out.
// R16: attn reverted to R10 exactly (best measured: 43.4us; six structural
//      variants R9-R15 all land 43-47 with MfmaUtil pinned ~28 -- R10's
//      V-in-LDS + 4-wave + exp||qk||pv pipeline + 4-deep staging wins) plus
//      one mechanical trim: hoisted zero f32x4 as C-operand of each chunk's
//      first MFMA per S accumulator (kills 64 v_mov/chunk/wave zero-init).
//      qkv V-epilogue restored to R10's permuted [B][H][Hd][S_perm] layout.
//      Session accounting: total = attn + ~47us (qkv/out/prep) + ~87.6us
//      harness workspace re-poison (uncontrollable). GEMMs = R6 exact.
// ---------------------------------------------------------------------------

using bf16   = __bf16;
using bf16x8 = __attribute__((ext_vector_type(8))) __bf16;
using bf16x4 = __attribute__((ext_vector_type(4))) __bf16;
using f32x4  = __attribute__((ext_vector_type(4))) float;

#define MFMA16(a, b, c) __builtin_amdgcn_mfma_f32_16x16x32_bf16((a), (b), (c), 0, 0, 0)
#define WAIT_VM0() asm volatile("s_waitcnt vmcnt(0)" ::: "memory")
#define WAITBAR(N) asm volatile("s_waitcnt vmcnt(" #N ")\n\ts_barrier" ::: "memory")

__device__ __forceinline__ bf16x8 ld8(const bf16* p) { return *(const bf16x8*)p; }

// async global->LDS, 16B/lane; lds_base is wave-uniform, HW adds lane*16.
__device__ __forceinline__ void ldg_lds16(bf16* lds_base, const bf16* g) {
    __builtin_amdgcn_global_load_lds(
        (const __attribute__((address_space(1))) void*)g,
        (__attribute__((address_space(3))) void*)lds_base, 16, 0, 0);
}

__device__ __forceinline__ float fast_exp2(float x) {
#if __has_builtin(__builtin_amdgcn_exp2f)
    return __builtin_amdgcn_exp2f(x);
#else
    return exp2f(x);
#endif
}

// ---------------------------------------------------------------------------
// Merged prep: z=0..3 transpose+convert W*; z=4 convert x -> bf16.
// ---------------------------------------------------------------------------
__global__ __launch_bounds__(256) void prep_kernel(
    const float* __restrict__ x, const float* __restrict__ Wq,
    const float* __restrict__ Wk, const float* __restrict__ Wv,
    const float* __restrict__ Wo, bf16* __restrict__ xb,
    bf16* __restrict__ WtBase) {
    const int z = blockIdx.z;
    const int tid = threadIdx.x;
    if (z == 4) {
        int id = blockIdx.y * 32 + blockIdx.x;      // 0..1023
#pragma unroll
        for (int k = 0; k < 4; ++k) {
            int i = id * 4096 + k * 1024 + tid * 4;
            float4 v = *(const float4*)&x[i];
            bf16x4 o = { (bf16)v.x, (bf16)v.y, (bf16)v.z, (bf16)v.w };
            *(bf16x4*)&xb[i] = o;
        }
        return;
    }
    __shared__ float tile[32][33];
    const float* W = (z == 0) ? Wq : (z == 1) ? Wk : (z == 2) ? Wv : Wo;
    bf16* Wt = WtBase + (size_t)z * 1024 * 1024;
    const int tx = tid & 31, ty = tid >> 5;          // 32 x 8
    const int x0 = blockIdx.x * 32, y0 = blockIdx.y * 32;
#pragma unroll
    for (int i = 0; i < 4; ++i)
        tile[ty + i * 8][tx] = W[(size_t)(y0 + ty + i * 8) * 1024 + x0 + tx];
    __syncthreads();
#pragma unroll
    for (int i = 0; i < 4; ++i)
        Wt[(size_t)(x0 + ty + i * 8) * 1024 + y0 + tx] = (bf16)tile[tx][ty + i * 8];
}

// ---------------------------------------------------------------------------
// 128x128 GEMM core, async double-buffered (R6 exact).
// ---------------------------------------------------------------------------
__device__ __forceinline__ void gemm_stage(const bf16* __restrict__ src, int r0,
                                           int k0, bf16* dst, int w, int lane) {
#pragma unroll
    for (int c = 0; c < 2; ++c) {
        int flat = (w * 2 + c) * 64 + lane;
        int row = flat >> 2, cc = flat & 3;
        int gk = (cc ^ ((row >> 1) & 3)) * 8;
        ldg_lds16(dst + (size_t)(w * 2 + c) * 512,
                  src + (size_t)(r0 + row) * 1024 + k0 + gk);
    }
}

__device__ __forceinline__ void gemm_core_128(const bf16* __restrict__ A,
                                              const bf16* __restrict__ Bt,
                                              int m0, int n0,
                                              bf16* As, bf16* Bs,   // each 2*4096
                                              f32x4 (&acc)[4][4]) {
    const int tid = threadIdx.x, lane = tid & 63, w = tid >> 6;
    const int lo = lane & 15, quad = lane >> 4;
    const int wm = w >> 1, wn = w & 1;

    gemm_stage(A,  m0, 0, As, w, lane);
    gemm_stage(Bt, n0, 0, Bs, w, lane);
    WAIT_VM0();
    __syncthreads();

    for (int it = 0; it < 32; ++it) {
        const int buf = it & 1;
        if (it + 1 < 32) {
            gemm_stage(A,  m0, (it + 1) * 32, As + (buf ^ 1) * 4096, w, lane);
            gemm_stage(Bt, n0, (it + 1) * 32, Bs + (buf ^ 1) * 4096, w, lane);
        }
        const bf16* Ab = As + buf * 4096;
        const bf16* Bb = Bs + buf * 4096;
        bf16x8 af[4], bq[4];
#pragma unroll
        for (int t = 0; t < 4; ++t) {
            int r = wm * 64 + t * 16 + lo;
            af[t] = ld8(&Ab[r * 32 + ((quad ^ ((r >> 1) & 3)) * 8)]);
        }
#pragma unroll
        for (int t = 0; t < 4; ++t) {
            int r = wn * 64 + t * 16 + lo;
            bq[t] = ld8(&Bb[r * 32 + ((quad ^ ((r >> 1) & 3)) * 8)]);
        }
#pragma unroll
        for (int mt = 0; mt < 4; ++mt)
#pragma unroll
            for (int nt = 0; nt < 4; ++nt)
                acc[mt][nt] = MFMA16(af[mt], bq[nt], acc[mt][nt]);
        WAIT_VM0();
        __syncthreads();
    }
}

// Fused QKV projection. z=0 -> Q (scaled log2e/8), z=1 -> K, z=2 -> V
// transposed [B][H][Hd][S_perm] via LDS-transpose epilogue; the s coordinate
// is permuted within each 32-key group: col' keeps attn's PV slot mapping
// slot = quad*8 + T*4 + o  <->  key = T*16 + quad*4 + o.
__global__ __launch_bounds__(256, 3) void qkv_gemm_kernel(
    const bf16* __restrict__ Xb, const bf16* __restrict__ Wts,
    const float* __restrict__ bq, const float* __restrict__ bk,
    const float* __restrict__ bv,
    bf16* __restrict__ Qo, bf16* __restrict__ Ko, bf16* __restrict__ Vto) {
    __shared__ bf16 Smem[4 * 4096];
    bf16* As = Smem;
    bf16* Bs = Smem + 2 * 4096;
    const int z = blockIdx.z;
    const bf16*  Bt   = Wts + (size_t)z * 1024 * 1024;
    const float* bias = (z == 0) ? bq : (z == 1) ? bk : bv;
    const int m0 = blockIdx.y * 128, n0 = blockIdx.x * 128;

    f32x4 acc[4][4] = {};
    gemm_core_128(Xb, Bt, m0, n0, As, Bs, acc);

    const int tid = threadIdx.x;
    const int lane = tid & 63, w = tid >> 6;
    const int lo = lane & 15, quad = lane >> 4;
    const int wm = w >> 1, wn = w & 1;
    const float QSCALE = 0.125f * 1.44269504088896f;  // 1/sqrt(64) * log2(e)

    if (z == 2) {
        // ---- V: transpose via LDS (two 128n x 64m half-tiles, stride 68) ----
        bf16* T = Smem;                      // 128*68 = 8704 elems
        const int b = m0 >> 11;
        const int s_base = m0 & 2047;
#pragma unroll
        for (int half = 0; half < 2; ++half) {
            __syncthreads();
            if (wm == half) {
#pragma unroll
                for (int nt = 0; nt < 4; ++nt)
#pragma unroll
                    for (int mt = 0; mt < 4; ++mt)
#pragma unroll
                        for (int r = 0; r < 4; ++r) {
                            int nn = wn * 64 + nt * 16 + lo;
                            int mm = mt * 16 + quad * 4 + r;
                            T[nn * 68 + mm] = (bf16)(acc[mt][nt][r] + bias[n0 + nn]);
                        }
            }
            __syncthreads();
#pragma unroll
            for (int p = 0; p < 8; ++p) {
                int pos = p * 1024 + tid * 4;
                int row = pos >> 6, col = pos & 63;
                int n = n0 + row, h = n >> 6, hd = n & 63;
                // permute key within its 32-group: slot = q4*8 + T16*4 + o
                int colp = (col & 32) | (((col >> 2) & 3) << 3)
                         | (((col >> 4) & 1) << 2) | (col & 3);
                bf16x4 v = *(const bf16x4*)&T[row * 68 + col];
                *(bf16x4*)&Vto[((size_t)((b * 16 + h) * 64 + hd) << 11)
                               + s_base + half * 64 + colp] = v;
            }
        }
    } else {
#pragma unroll
        for (int mt = 0; mt < 4; ++mt)
#pragma unroll
            for (int nt = 0; nt < 4; ++nt)
#pragma unroll
                for (int r = 0; r < 4; ++r) {
                    int m = m0 + wm * 64 + mt * 16 + quad * 4 + r;
                    int n = n0 + wn * 64 + nt * 16 + lo;
                    float v = acc[mt][nt][r] + bias[n];
                    int b = m >> 11, s = m & 2047, h = n >> 6, hd = n & 63;
                    if (z == 0)
                        Qo[((size_t)((b * 16 + h) * 2048 + s) << 6) + hd] = (bf16)(v * QSCALE);
                    else
                        Ko[((size_t)((b * 16 + h) * 2048 + s) << 6) + hd] = (bf16)v;
                }
    }
}

// ---------------------------------------------------------------------------
// Output projection, 64x128 tiles (512 blocks = 2/CU), double-buffered (R6).
// ---------------------------------------------------------------------------
__global__ __launch_bounds__(256, 2) void out_gemm_kernel(
    const bf16* __restrict__ A, const bf16* __restrict__ Bt,
    const float* __restrict__ bo, float* __restrict__ Co) {
    __shared__ bf16 As[2 * 2048];
    __shared__ bf16 Bs[2 * 4096];
    const int tid = threadIdx.x, lane = tid & 63, w = tid >> 6;
    const int lo = lane & 15, quad = lane >> 4;
    const int wm = w >> 1, wn = w & 1;
    const int m0 = blockIdx.y * 64, n0 = blockIdx.x * 128;

    auto stageA = [&](int k0, bf16* dst) {
        int flat = w * 64 + lane;
        int row = flat >> 2, cc = flat & 3;
        int gk = (cc ^ ((row >> 1) & 3)) * 8;
        ldg_lds16(dst + (size_t)w * 512, A + (size_t)(m0 + row) * 1024 + k0 + gk);
    };
    auto stageB = [&](int k0, bf16* dst) {
#pragma unroll
        for (int c = 0; c < 2; ++c) {
            int flat = (w * 2 + c) * 64 + lane;
            int row = flat >> 2, cc = flat & 3;
            int gk = (cc ^ ((row >> 1) & 3)) * 8;
            ldg_lds16(dst + (size_t)(w * 2 + c) * 512,
                      Bt + (size_t)(n0 + row) * 1024 + k0 + gk);
        }
    };

    f32x4 acc[2][4] = {};
    stageA(0, As);
    stageB(0, Bs);
    WAIT_VM0();
    __syncthreads();

    for (int it = 0; it < 32; ++it) {
        const int buf = it & 1;
        if (it + 1 < 32) {
            stageA((it + 1) * 32, As + (buf ^ 1) * 2048);
            stageB((it + 1) * 32, Bs + (buf ^ 1) * 4096);
        }
        const bf16* Ab = As + buf * 2048;
        const bf16* Bb = Bs + buf * 4096;
        bf16x8 af[2], bq[4];
#pragma unroll
        for (int t = 0; t < 2; ++t) {
            int r = wm * 32 + t * 16 + lo;
            af[t] = ld8(&Ab[r * 32 + ((quad ^ ((r >> 1) & 3)) * 8)]);
        }
#pragma unroll
        for (int t = 0; t < 4; ++t) {
            int r = wn * 64 + t * 16 + lo;
            bq[t] = ld8(&Bb[r * 32 + ((quad ^ ((r >> 1) & 3)) * 8)]);
        }
#pragma unroll
        for (int mt = 0; mt < 2; ++mt)
#pragma unroll
            for (int nt = 0; nt < 4; ++nt)
                acc[mt][nt] = MFMA16(af[mt], bq[nt], acc[mt][nt]);
        WAIT_VM0();
        __syncthreads();
    }

#pragma unroll
    for (int mt = 0; mt < 2; ++mt)
#pragma unroll
        for (int nt = 0; nt < 4; ++nt)
#pragma unroll
            for (int r = 0; r < 4; ++r) {
                int m = m0 + wm * 32 + mt * 16 + quad * 4 + r;
                int n = n0 + wn * 64 + nt * 16 + lo;
                Co[(size_t)m * 1024 + n] = acc[mt][nt][r] + bo[n];
            }
}

// ---------------------------------------------------------------------------
// Flash attention R16 (= R10 + hoisted-zero S init): software-pipelined S^T.
// Grid 512 x 256 (4 waves, 2 blk/CU). Block = 128 q-rows of one (b,h); each
// wave owns 32 q. 64-key chunks, K+V 4-deep LDS (64KB), staged 2 ahead,
// 4 ldg_lds/wave/chunk, counted WAITBAR(4). Per iteration (one region):
//   exp(S_i) [VALU] || S_{i+1}=K*Q^T [MFMA+LDS] || O+=P_i*V_i [MFMA+LDS]
// S ping-pongs Sa/Sb. First MFMA per S accumulator takes the hoisted zero
// f32x4 as C (no per-chunk zero-init movs).
// ---------------------------------------------------------------------------
__global__ __launch_bounds__(256, 2) void attn_kernel(
    const bf16* __restrict__ Q, const bf16* __restrict__ K,
    const bf16* __restrict__ Vt, bf16* __restrict__ AO) {
    __shared__ bf16 Ks[4][64 * 64];
    __shared__ bf16 Vs[4][64 * 64];
    const int tid = threadIdx.x, w = tid >> 6, lane = tid & 63;
    const int lo = lane & 15, quad = lane >> 4;
    const int blk = blockIdx.x;
    const int bh = (blk & 7) | ((blk >> 7) << 3);  // same-head -> same XCD
    const int qb = (blk >> 3) & 15;
    const int q0 = qb * 128 + w * 32;

    const bf16* Qb = Q + ((size_t)bh * 2048 + q0) * 64;
    const bf16* Kb = K + (size_t)bh * 2048 * 64;
    const bf16* Vb = Vt + (size_t)bh * 64 * 2048;

    // Q B-fragments: n-row = qt*16+lo, k = ks*32+quad*8
    bf16x8 qa[2][2];
#pragma unroll
    for (int qt = 0; qt < 2; ++qt)
#pragma unroll
        for (int ks = 0; ks < 2; ++ks)
            qa[qt][ks] = ld8(&Qb[(qt * 16 + lo) * 64 + ks * 32 + quad * 8]);

    f32x4 O[2][4] = {};
    float l_acc[2] = { 0.f, 0.f };
    const f32x4 ZERO = { 0.f, 0.f, 0.f, 0.f };   // hoisted C-operand

    // stage one 64-key K+V chunk (4 ldg_lds/wave); swizzle s(row)=row&7 both.
    auto stage = [&](int s0, int buf) {
#pragma unroll
        for (int c = 0; c < 2; ++c) {
            int flat = (w * 2 + c) * 64 + lane;
            int row = flat >> 3, cc = flat & 7;
            int g = (cc ^ (row & 7)) * 8;
            ldg_lds16(&Ks[buf][(w * 2 + c) * 512], &Kb[(size_t)(s0 + row) * 64 + g]);
            ldg_lds16(&Vs[buf][(w * 2 + c) * 512], &Vb[(size_t)row * 2048 + s0 + g]);
        }
    };

    const int swz = lo & 7;  // read-side swizzle for rows t*16+lo

    // ---- S^T = K * Q^T from Ks[nb] : 4 key m-tiles x 2 q n-tiles x 2 k ----
    auto qk = [&](int nb, f32x4 (&S)[2][4]) {
        const bf16* Kt = &Ks[nb][0];
#pragma unroll
        for (int t = 0; t < 4; ++t) {
            int r = t * 16 + lo;
            bf16x8 kf0 = ld8(&Kt[r * 64 + ((quad ^ swz) * 8)]);
            S[0][t] = MFMA16(kf0, qa[0][0], ZERO);
            S[1][t] = MFMA16(kf0, qa[1][0], ZERO);
            bf16x8 kf1 = ld8(&Kt[r * 64 + (((quad + 4) ^ swz) * 8)]);
            S[0][t] = MFMA16(kf1, qa[0][1], S[0][t]);
            S[1][t] = MFMA16(kf1, qa[1][1], S[1][t]);
        }
    };

    // ---- exp(Sin) -> pa (PV A-frags, keys slot-permuted) + l_acc ----
    auto expP = [&](f32x4 (&Sin)[2][4], bf16x8 (&pa)[2][2]) {
#pragma unroll
        for (int qt = 0; qt < 2; ++qt)
#pragma unroll
            for (int kc = 0; kc < 2; ++kc) {
                float e0 = fast_exp2(Sin[qt][2 * kc][0]);
                float e1 = fast_exp2(Sin[qt][2 * kc][1]);
                float e2 = fast_exp2(Sin[qt][2 * kc][2]);
                float e3 = fast_exp2(Sin[qt][2 * kc][3]);
                float e4 = fast_exp2(Sin[qt][2 * kc + 1][0]);
                float e5 = fast_exp2(Sin[qt][2 * kc + 1][1]);
                float e6 = fast_exp2(Sin[qt][2 * kc + 1][2]);
                float e7 = fast_exp2(Sin[qt][2 * kc + 1][3]);
                l_acc[qt] += ((e0 + e1) + (e2 + e3)) + ((e4 + e5) + (e6 + e7));
                pa[qt][kc] = bf16x8{ (bf16)e0, (bf16)e1, (bf16)e2, (bf16)e3,
                                     (bf16)e4, (bf16)e5, (bf16)e6, (bf16)e7 };
            }
    };

    // ---- PV from Vs[cb] ----
    auto pv = [&](int cb, bf16x8 (&pa)[2][2]) {
        const bf16* Vl = &Vs[cb][0];
#pragma unroll
        for (int kc = 0; kc < 2; ++kc)
#pragma unroll
            for (int nt = 0; nt < 4; ++nt) {
                int r = nt * 16 + lo;
                bf16x8 vf = ld8(&Vl[r * 64 + ((((kc * 4 + quad) ^ swz)) * 8)]);
                O[0][nt] = MFMA16(pa[0][kc], vf, O[0][nt]);
                O[1][nt] = MFMA16(pa[1][kc], vf, O[1][nt]);
            }
    };

    // step i: exp(S_i) || S_{i+1}=qk || O+=P_i*V_i  (one region, no barrier)
    auto step = [&](f32x4 (&Sin)[2][4], f32x4 (&Sout)[2][4], int cb, int nb) {
        bf16x8 pa[2][2];
        expP(Sin, pa);
        qk(nb, Sout);
        pv(cb, pa);
    };

    stage(0, 0);
    stage(64, 1);
    WAITBAR(4);                     // chunk0 ready; chunk1 in flight

    f32x4 Sa[2][4], Sb[2][4];
    qk(0, Sa);

    for (int it = 0; it < 30; it += 2) {
        stage((it + 2) * 64, (it + 2) & 3);
        WAITBAR(4);                 // chunk it+1 ready
        step(Sa, Sb, it & 3, (it + 1) & 3);
        stage((it + 3) * 64, (it + 3) & 3);
        WAITBAR(4);                 // chunk it+2 ready
        step(Sb, Sa, (it + 1) & 3, (it + 2) & 3);
    }
    WAITBAR(0);                     // chunk 31 ready
    step(Sa, Sb, 2, 3);             // exp(S30) || qk(31) || PV(30)
    {                               // tail: exp(S31) + PV(31)
        bf16x8 pa[2][2];
        expP(Sb, pa);
        pv(3, pa);
    }

    // ---- epilogue: l lives at q=lo; redistribute to C-rows via shfl ----
    const int bb = bh >> 4, h = bh & 15;
#pragma unroll
    for (int qt = 0; qt < 2; ++qt) {
        float lt = l_acc[qt];
        lt += __shfl_xor(lt, 16, 64);
        lt += __shfl_xor(lt, 32, 64);   // total l for q = qt*16 + lo
        const size_t outbase = ((size_t)(bb * 2048 + q0 + qt * 16)) * 1024 + h * 64;
#pragma unroll
        for (int r = 0; r < 4; ++r) {
            float rl = 1.0f / __shfl(lt, quad * 4 + r, 64);
            size_t rowoff = outbase + (size_t)(quad * 4 + r) * 1024;
#pragma unroll
            for (int nt = 0; nt < 4; ++nt)
                AO[rowoff + nt * 16 + lo] = (bf16)(O[qt][nt][r] * rl);
        }
    }
}

// ---------------------------------------------------------------------------
extern "C" void kernel_launch(void* const* d_in, const int* in_sizes, int n_in,
                              void* d_out, int out_size, void* d_ws, size_t ws_size,
                              hipStream_t stream) {
    const float* x  = (const float*)d_in[0];
    const float* Wq = (const float*)d_in[1];
    const float* bq = (const float*)d_in[2];
    const float* Wk = (const float*)d_in[3];
    const float* bk = (const float*)d_in[4];
    const float* Wv = (const float*)d_in[5];
    const float* bv = (const float*)d_in[6];
    const float* Wo = (const float*)d_in[7];
    const float* bo = (const float*)d_in[8];
    float* out = (float*)d_out;

    bf16* wsb = (bf16*)d_ws;
    const size_t M1 = 1024u * 1024u;
    bf16* Xb  = wsb;
    bf16* AO  = wsb;            // aliases Xb (Xb dead after qkv_gemm)
    bf16* Wt  = wsb + 4 * M1;
    bf16* Qw  = wsb + 8 * M1;
    bf16* Kw  = wsb + 12 * M1;
    bf16* Vtw = wsb + 16 * M1;

    prep_kernel<<<dim3(32, 32, 5), 256, 0, stream>>>(x, Wq, Wk, Wv, Wo, Xb, Wt);
    qkv_gemm_kernel<<<dim3(8, 32, 3), 256, 0, stream>>>(Xb, Wt, bq, bk, bv, Qw, Kw, Vtw);
    attn_kernel<<<512, 256, 0, stream>>>(Qw, Kw, Vtw, AO);
    out_gemm_kernel<<<dim3(8, 64), 256, 0, stream>>>(AO, Wt + 3 * M1, bo, out);
}